// Round 1
// baseline (6510.979 us; speedup 1.0000x reference)
//
#include <hip/hip_runtime.h>
#include <math.h>

// ---------------------------------------------------------------------------
// DiffPool GNN (N=8192, E=262144, F=H=128, C1=1024, C2=128, NC=16), fp32.
// Strategy: never read dense adj (edge-list equivalent); feature-commute the
// sparse aggregations to 128/16 features; link-loss via Frobenius expansion.
// ---------------------------------------------------------------------------

#define N_NODES 8192
#define N_EDGES 262144

// ---------------- workspace layout (float offsets) ----------------
#define OFF_DEG     0           // 8192  (zeroed)
#define OFF_CNTC    8192        // 8192  (zeroed)
#define OFF_CNTR    16384       // 8192  (zeroed)
#define OFF_SCAL    24576       // 16    (zeroed)  [0]=e1 [1]=cross [2]=g2 [3]=sumA2 [4]=l2 [5]=e2
#define ZERO_FLOATS 24592
#define OFF_COLPTR  24592       // 8193
#define OFF_ROWPTR  32785       // 8193
#define OFF_CURC    40978       // 8192
#define OFF_CURR    49170       // 8192
#define OFF_COLR    57362       // E (int)
#define OFF_COLN    319506      // E
#define OFF_ROWC    581650      // E (int)
#define OFF_ROWW    843794      // E
#define OFF_DINV    1105938     // 8192
#define OFF_X0      1114130     // 8192*128
#define OFF_H0      2162706     // 8192*128 (h0, later reused as z)
#define OFF_S       3211282     // 8192*1024 (softmax(s1)*mask)
#define OFF_T       11599890    // 8192*1024 (t = A@S); region reused after adj1:
#define OFF_X1      (OFF_T+0)         // 1024*128
#define OFF_AN1     (OFF_T+131072)    // 1024*1024
#define OFF_HA      (OFF_T+1179648)   // 1024*128
#define OFF_X1_     (OFF_T+1310720)   // 1024*128
#define OFF_HB      (OFF_T+1441792)   // 1024*128
#define OFF_S2      (OFF_T+1572864)   // 1024*128
#define OFF_S2S     (OFF_T+1703936)   // 1024*128
#define OFF_U       (OFF_T+1835008)   // 1024*128
#define OFF_X2      (OFF_T+1966080)   // 128*128
#define OFF_ADJ2    (OFF_T+1982464)   // 128*128
#define OFF_HC      (OFF_T+1998848)   // 128*128
#define OFF_X2_     (OFF_T+2015232)   // 128*128
#define OFF_AN2     (OFF_T+2031616)   // 128*128
#define OFF_X2UP    (OFF_T+2048000)   // 1024*128
#define OFF_HCAT    (OFF_T+2179072)   // 1024*128
#define OFF_X1O     (OFF_T+2310144)   // 1024*128
#define OFF_X1UP    (OFF_T+2441216)   // 8192*128
#define OFF_P16     (OFF_T+3489792)   // 8192*16
#define OFF_H16     (OFF_T+3620864)   // 8192*16
#define OFF_DI1     (OFF_T+3751936)   // 1024
#define OFF_DF1     (OFF_T+3752960)   // 1024
#define OFF_DI2     (OFF_T+3753984)   // 128
#define OFF_DF2     (OFF_T+3754112)   // 128
// total ws: 19,988,498 floats ≈ 76.3 MiB

// ------------------- output layout (floats) -------------------
#define OUT_PRED 0          // 8192*16
#define OUT_S1   131072     // 8192*1024
#define OUT_LOSS 8519680    // 1
#define OUT_ADJ1 8519681    // 1024*1024

// =========================== kernels ===========================

// histogram of edge endpoints + weighted degree at col + sum(w^2)
__global__ void k_hist(const int* __restrict__ row, const int* __restrict__ col,
                       const float* __restrict__ ew, int E,
                       float* deg, int* cntc, int* cntr, float* sumA2) {
    __shared__ float red[256];
    int e = blockIdx.x * 256 + threadIdx.x;
    float w2 = 0.f;
    if (e < E) {
        int r = row[e], c = col[e];
        float w = ew[e];
        atomicAdd(&deg[c], w);
        atomicAdd(&cntc[c], 1);
        atomicAdd(&cntr[r], 1);
        w2 = w * w;
    }
    red[threadIdx.x] = w2; __syncthreads();
    for (int s = 128; s > 0; s >>= 1) { if (threadIdx.x < s) red[threadIdx.x] += red[threadIdx.x + s]; __syncthreads(); }
    if (threadIdx.x == 0) atomicAdd(sumA2, red[0]);
}

__global__ void k_dinv(const float* deg, float* dinv, int n) {
    int i = blockIdx.x * 256 + threadIdx.x;
    if (i < n) {
        float d = deg[i] + 1.0f;     // +1 self loop
        dinv[i] = (d > 0.f) ? 1.0f / sqrtf(d) : 0.f;
    }
}

// single-block exclusive scan of both count arrays (n=8192, 1024 threads)
__global__ __launch_bounds__(1024) void k_scan(const int* cntc, const int* cntr,
        int* colptr, int* rowptr, int* curc, int* curr, int n, int E) {
    __shared__ int part[1024];
    int tid = threadIdx.x;
    const int per = 8;  // n / 1024
    for (int pass = 0; pass < 2; ++pass) {
        const int* cnt = pass ? cntr : cntc;
        int* ptr = pass ? rowptr : colptr;
        int* cur = pass ? curr : curc;
        int st = tid * per;
        int loc[per]; int s = 0;
        for (int i = 0; i < per; ++i) { loc[i] = s; s += cnt[st + i]; }
        part[tid] = s; __syncthreads();
        for (int off = 1; off < 1024; off <<= 1) {
            int v = part[tid];
            int add = (tid >= off) ? part[tid - off] : 0;
            __syncthreads();
            part[tid] = v + add;
            __syncthreads();
        }
        int pre = (tid == 0) ? 0 : part[tid - 1];
        for (int i = 0; i < per; ++i) { int v = pre + loc[i]; ptr[st + i] = v; cur[st + i] = v; }
        if (tid == 0) ptr[n] = E;
        __syncthreads();
    }
}

__global__ void k_scatter(const int* __restrict__ row, const int* __restrict__ col,
                          const float* __restrict__ ew, int E, const float* __restrict__ dinv,
                          int* curc, int* curr, int* colr, float* coln, int* rowc, float* roww) {
    int e = blockIdx.x * 256 + threadIdx.x;
    if (e >= E) return;
    int r = row[e], c = col[e];
    float w = ew[e];
    float nrm = dinv[r] * w * dinv[c];
    int p = atomicAdd(&curc[c], 1);
    colr[p] = r; coln[p] = nrm;
    int q = atomicAdd(&curr[r], 1);
    rowc[q] = c; roww[q] = w;
}

// C[M,N] = A[M,K] @ B[K,N]  (+accum, +bias, +relu)
__global__ __launch_bounds__(256) void gemm_ab(const float* __restrict__ A, const float* __restrict__ B,
        float* __restrict__ C, int M, int N, int K,
        const float* __restrict__ bias, int relu, int accum) {
    __shared__ float As[16][68];
    __shared__ float Bs[16][68];
    int tid = threadIdx.x, tx = tid & 15, ty = tid >> 4;
    int m0 = blockIdx.y * 64, n0 = blockIdx.x * 64;
    float acc[4][4] = {};
    for (int k0 = 0; k0 < K; k0 += 16) {
        for (int l = 0; l < 4; ++l) {
            int idx = tid + 256 * l;
            int mm = idx >> 4, kk = idx & 15;
            int m = m0 + mm, k = k0 + kk;
            As[kk][mm] = (m < M && k < K) ? A[(size_t)m * K + k] : 0.f;
            int kk2 = idx >> 6, nn = idx & 63;
            int k2 = k0 + kk2, n = n0 + nn;
            Bs[kk2][nn] = (k2 < K && n < N) ? B[(size_t)k2 * N + n] : 0.f;
        }
        __syncthreads();
        #pragma unroll
        for (int kk = 0; kk < 16; ++kk) {
            float a[4], b[4];
            #pragma unroll
            for (int i = 0; i < 4; ++i) a[i] = As[kk][ty * 4 + i];
            #pragma unroll
            for (int j = 0; j < 4; ++j) b[j] = Bs[kk][tx * 4 + j];
            #pragma unroll
            for (int i = 0; i < 4; ++i)
                #pragma unroll
                for (int j = 0; j < 4; ++j) acc[i][j] += a[i] * b[j];
        }
        __syncthreads();
    }
    for (int i = 0; i < 4; ++i) {
        int m = m0 + ty * 4 + i; if (m >= M) continue;
        for (int j = 0; j < 4; ++j) {
            int n = n0 + tx * 4 + j; if (n >= N) continue;
            float v = acc[i][j];
            if (accum) v += C[(size_t)m * N + n];
            if (bias) v += bias[n];
            if (relu) v = fmaxf(v, 0.f);
            C[(size_t)m * N + n] = v;
        }
    }
}

// C[M,N] = A^T @ B  with A[K,M], B[K,N] (K-major).  Options:
//   rowscaleB: B[k,:] *= rs[k];  sumsq: skip store, atomicAdd sum(C^2).
__global__ __launch_bounds__(256) void gemm_atb(const float* __restrict__ A, const float* __restrict__ B,
        float* __restrict__ C, int M, int N, int K,
        const float* __restrict__ bias, int relu,
        const float* __restrict__ rowscaleB, float* sumsq_acc) {
    __shared__ float As[16][68];
    __shared__ float Bs[16][68];
    __shared__ float red[256];
    int tid = threadIdx.x, tx = tid & 15, ty = tid >> 4;
    int m0 = blockIdx.y * 64, n0 = blockIdx.x * 64;
    float acc[4][4] = {};
    for (int k0 = 0; k0 < K; k0 += 16) {
        for (int l = 0; l < 4; ++l) {
            int idx = tid + 256 * l;
            int kk = idx >> 6, mm = idx & 63;
            int k = k0 + kk;
            int m = m0 + mm;
            As[kk][mm] = (k < K && m < M) ? A[(size_t)k * M + m] : 0.f;
            int n = n0 + mm;
            float bv = 0.f;
            if (k < K && n < N) {
                bv = B[(size_t)k * N + n];
                if (rowscaleB) bv *= rowscaleB[k];
            }
            Bs[kk][mm] = bv;
        }
        __syncthreads();
        #pragma unroll
        for (int kk = 0; kk < 16; ++kk) {
            float a[4], b[4];
            #pragma unroll
            for (int i = 0; i < 4; ++i) a[i] = As[kk][ty * 4 + i];
            #pragma unroll
            for (int j = 0; j < 4; ++j) b[j] = Bs[kk][tx * 4 + j];
            #pragma unroll
            for (int i = 0; i < 4; ++i)
                #pragma unroll
                for (int j = 0; j < 4; ++j) acc[i][j] += a[i] * b[j];
        }
        __syncthreads();
    }
    if (sumsq_acc) {
        float ss = 0.f;
        for (int i = 0; i < 4; ++i) {
            int m = m0 + ty * 4 + i; if (m >= M) continue;
            for (int j = 0; j < 4; ++j) {
                int n = n0 + tx * 4 + j; if (n >= N) continue;
                ss += acc[i][j] * acc[i][j];
            }
        }
        red[tid] = ss; __syncthreads();
        for (int s = 128; s > 0; s >>= 1) { if (tid < s) red[tid] += red[tid + s]; __syncthreads(); }
        if (tid == 0) atomicAdd(sumsq_acc, red[0]);
    } else {
        for (int i = 0; i < 4; ++i) {
            int m = m0 + ty * 4 + i; if (m >= M) continue;
            for (int j = 0; j < 4; ++j) {
                int n = n0 + tx * 4 + j; if (n >= N) continue;
                float v = acc[i][j];
                if (bias) v += bias[n];
                if (relu) v = fmaxf(v, 0.f);
                C[(size_t)m * N + n] = v;
            }
        }
    }
}

// GCN sparse aggregation at target node c (CSC), + self-loop, + bias/relu.
__global__ void k_agg(const float* __restrict__ h, float* __restrict__ out,
                      const int* __restrict__ cptr, const int* __restrict__ colr,
                      const float* __restrict__ coln, const float* __restrict__ dinv,
                      int F, const float* __restrict__ bias, int relu) {
    int c = blockIdx.x;
    int f = threadIdx.x;
    if (f >= F) return;
    float d = dinv[c];
    float acc = d * d * h[(size_t)c * F + f];
    int e0 = cptr[c], e1 = cptr[c + 1];
    for (int e = e0; e < e1; ++e)
        acc += coln[e] * h[(size_t)colr[e] * F + f];
    if (bias) acc += bias[f];
    if (relu) acc = fmaxf(acc, 0.f);
    out[(size_t)c * F + f] = acc;
}

// row softmax (* optional mask) + entropy accumulation
__global__ __launch_bounds__(256) void k_softmax_ent(const float* __restrict__ x, float* __restrict__ S,
        int W, const float* __restrict__ mask, float* ent_acc) {
    __shared__ float red[256];
    int row = blockIdx.x, tid = threadIdx.x;
    const float* xr = x + (size_t)row * W;
    float m = -3.0e38f;
    for (int q = tid; q < W; q += 256) m = fmaxf(m, xr[q]);
    red[tid] = m; __syncthreads();
    for (int s = 128; s > 0; s >>= 1) { if (tid < s) red[tid] = fmaxf(red[tid], red[tid + s]); __syncthreads(); }
    m = red[0]; __syncthreads();
    float sum = 0.f;
    for (int q = tid; q < W; q += 256) sum += expf(xr[q] - m);
    red[tid] = sum; __syncthreads();
    for (int s = 128; s > 0; s >>= 1) { if (tid < s) red[tid] += red[tid + s]; __syncthreads(); }
    float inv = 1.0f / red[0]; __syncthreads();
    float mk = mask ? mask[row] : 1.0f;
    float* Sr = S + (size_t)row * W;
    float ent = 0.f;
    for (int q = tid; q < W; q += 256) {
        float v = expf(xr[q] - m) * inv * mk;
        Sr[q] = v;
        ent -= v * logf(v + 1e-15f);
    }
    red[tid] = ent; __syncthreads();
    for (int s = 128; s > 0; s >>= 1) { if (tid < s) red[tid] += red[tid + s]; __syncthreads(); }
    if (tid == 0) atomicAdd(ent_acc, red[0]);
}

// t[r,:] = sum_{e in row r} w_e * S[c_e,:]   (CSR), plus
// cross += sum_e w_e * dot(S[r],S[c])   (the <A, S S^T> term of the link loss)
__global__ __launch_bounds__(256) void k_spmm(const float* __restrict__ S,
        const int* __restrict__ rptr, const int* __restrict__ rowc, const float* __restrict__ roww,
        float* __restrict__ t, float* cross_acc) {
    __shared__ float red[256];
    int r = blockIdx.x, tid = threadIdx.x;
    float acc[4] = {0.f, 0.f, 0.f, 0.f};
    float sr[4];
    const float* Srow = S + (size_t)r * 1024;
    #pragma unroll
    for (int j = 0; j < 4; ++j) sr[j] = Srow[tid + 256 * j];
    float lp = 0.f;
    int e0 = rptr[r], e1 = rptr[r + 1];
    for (int e = e0; e < e1; ++e) {
        int c = rowc[e]; float w = roww[e];
        const float* Sc = S + (size_t)c * 1024;
        #pragma unroll
        for (int j = 0; j < 4; ++j) {
            float v = Sc[tid + 256 * j];
            acc[j] += w * v;
            lp += w * sr[j] * v;
        }
    }
    float* tr = t + (size_t)r * 1024;
    #pragma unroll
    for (int j = 0; j < 4; ++j) tr[tid + 256 * j] = acc[j];
    red[tid] = lp; __syncthreads();
    for (int s = 128; s > 0; s >>= 1) { if (tid < s) red[tid] += red[tid + s]; __syncthreads(); }
    if (tid == 0) atomicAdd(cross_acc, red[0]);
}

// per-column: deg (colsum with add_remaining_self_loops fix) -> dinv, diagfix
__global__ void k_colprep(const float* __restrict__ adjm, int n, float* dinvv, float* dfix) {
    int j = blockIdx.x * blockDim.x + threadIdx.x;
    if (j >= n) return;
    float s = 0.f;
    for (int i = 0; i < n; ++i) s += adjm[(size_t)i * n + j];
    float diag = adjm[(size_t)j * n + j];
    float fix = (diag == 0.f) ? 1.0f : 0.f;
    s += fix;
    dfix[j] = fix;
    dinvv[j] = (s > 0.f) ? 1.0f / sqrtf(s) : 0.f;
}

__global__ void k_anorm(const float* __restrict__ adjm, int n, const float* __restrict__ dinvv,
                        const float* __restrict__ dfix, float* __restrict__ anorm) {
    int idx = blockIdx.x * 256 + threadIdx.x;
    if (idx >= n * n) return;
    int i = idx / n, j = idx % n;
    float v = adjm[idx] + ((i == j) ? dfix[j] : 0.f);
    anorm[idx] = dinvv[i] * v * dinvv[j];
}

// l2 += sum_pq (adj1[p,q] - dot(S2[p],S2[q]))^2
__global__ __launch_bounds__(128) void k_l2(const float* __restrict__ adjm, const float* __restrict__ S2,
        float* acc) {
    __shared__ float sp[128];
    __shared__ float red[128];
    int p = blockIdx.x, tid = threadIdx.x;
    sp[tid] = S2[(size_t)p * 128 + tid];
    __syncthreads();
    float part = 0.f;
    for (int q = tid; q < 1024; q += 128) {
        const float* Sq = S2 + (size_t)q * 128;
        float dot = 0.f;
        #pragma unroll 8
        for (int k = 0; k < 128; ++k) dot += Sq[k] * sp[k];
        float d = adjm[(size_t)p * 1024 + q] - dot;
        part += d * d;
    }
    red[tid] = part; __syncthreads();
    for (int s = 64; s > 0; s >>= 1) { if (tid < s) red[tid] += red[tid + s]; __syncthreads(); }
    if (tid == 0) atomicAdd(acc, red[0]);
}

__global__ void k_logsoftmax(const float* __restrict__ x, float* __restrict__ out, int n) {
    int i = blockIdx.x * 256 + threadIdx.x;
    if (i >= n) return;
    float v[16];
    float m = -3.0e38f;
    #pragma unroll
    for (int j = 0; j < 16; ++j) { v[j] = x[(size_t)i * 16 + j]; m = fmaxf(m, v[j]); }
    float s = 0.f;
    #pragma unroll
    for (int j = 0; j < 16; ++j) s += expf(v[j] - m);
    float ls = m + logf(s);
    #pragma unroll
    for (int j = 0; j < 16; ++j) out[(size_t)i * 16 + j] = v[j] - ls;
}

__global__ void k_finalize(const float* __restrict__ sc, float* loss) {
    if (threadIdx.x == 0 && blockIdx.x == 0) {
        float e1    = sc[0] / 8192.0f;
        float cross = sc[1];
        float g2    = sc[2];
        float sumA2 = sc[3];
        float l2s   = sc[4];
        float e2    = sc[5] / 1024.0f;
        float l1 = sqrtf(fmaxf(sumA2 - 2.0f * cross + g2, 0.f)) / 67108864.0f;  // / 8192^2
        float l2 = sqrtf(fmaxf(l2s, 0.f)) / 1048576.0f;                          // / 1024^2
        *loss = l1 + e1 + l2 + e2;
    }
}

// =========================== launcher ===========================

extern "C" void kernel_launch(void* const* d_in, const int* in_sizes, int n_in,
                              void* d_out, int out_size, void* d_ws, size_t ws_size,
                              hipStream_t stream) {
    const int N = N_NODES, E = N_EDGES;
    const float* x0     = (const float*)d_in[0];
    const int*   eidx   = (const int*)d_in[1];
    const float* ew     = (const float*)d_in[2];
    // d_in[3] = dense adj: intentionally unused (edge-list equivalent).
    const float* mask   = (const float*)d_in[4];
    const float* W0_in  = (const float*)d_in[5];
    const float* b0_in  = (const float*)d_in[6];
    const float* Wp1    = (const float*)d_in[7];
    const float* bp1    = (const float*)d_in[8];
    const float* W1_in  = (const float*)d_in[9];
    const float* b1_in  = (const float*)d_in[10];
    const float* Wp2    = (const float*)d_in[11];
    const float* bp2    = (const float*)d_in[12];
    const float* W2_in  = (const float*)d_in[13];
    const float* b2_in  = (const float*)d_in[14];
    const float* W1_out = (const float*)d_in[15];
    const float* b1_out = (const float*)d_in[16];
    const float* W0_out = (const float*)d_in[17];
    const float* b0_out = (const float*)d_in[18];

    float* out   = (float*)d_out;
    float* predo = out + OUT_PRED;
    float* s1o   = out + OUT_S1;
    float* losso = out + OUT_LOSS;
    float* adj1o = out + OUT_ADJ1;

    float* wsf = (float*)d_ws;
    int*   wsi = (int*)d_ws;
    float* deg   = wsf + OFF_DEG;
    int*   cntc  = wsi + OFF_CNTC;
    int*   cntr  = wsi + OFF_CNTR;
    float* scal  = wsf + OFF_SCAL;
    int*   cptr  = wsi + OFF_COLPTR;
    int*   rptr  = wsi + OFF_ROWPTR;
    int*   curc  = wsi + OFF_CURC;
    int*   curr  = wsi + OFF_CURR;
    int*   colr  = wsi + OFF_COLR;
    float* coln  = wsf + OFF_COLN;
    int*   rowc  = wsi + OFF_ROWC;
    float* roww  = wsf + OFF_ROWW;
    float* dinv  = wsf + OFF_DINV;
    float* x0_   = wsf + OFF_X0;
    float* h0    = wsf + OFF_H0;   // also z after x0_ is formed
    float* S     = wsf + OFF_S;
    float* t     = wsf + OFF_T;
    float* x1    = wsf + OFF_X1;
    float* an1   = wsf + OFF_AN1;
    float* hA    = wsf + OFF_HA;
    float* x1_   = wsf + OFF_X1_;
    float* hB    = wsf + OFF_HB;
    float* s2    = wsf + OFF_S2;
    float* S2s   = wsf + OFF_S2S;
    float* u     = wsf + OFF_U;
    float* x2    = wsf + OFF_X2;
    float* adj2  = wsf + OFF_ADJ2;
    float* hC    = wsf + OFF_HC;
    float* x2_   = wsf + OFF_X2_;
    float* an2   = wsf + OFF_AN2;
    float* x2up  = wsf + OFF_X2UP;
    float* hcat  = wsf + OFF_HCAT;
    float* x1o_  = wsf + OFF_X1O;
    float* x1up  = wsf + OFF_X1UP;
    float* p16   = wsf + OFF_P16;
    float* h16   = wsf + OFF_H16;
    float* di1   = wsf + OFF_DI1;
    float* df1   = wsf + OFF_DF1;
    float* di2   = wsf + OFF_DI2;
    float* df2   = wsf + OFF_DF2;

    const int* row = eidx;
    const int* col = eidx + E;

    // zero accumulators + histograms
    hipMemsetAsync(wsf, 0, (size_t)ZERO_FLOATS * sizeof(float), stream);

    // --- graph structure: degree, dinv, CSR/CSC ---
    k_hist<<<E / 256, 256, 0, stream>>>(row, col, ew, E, deg, cntc, cntr, &scal[3]);
    k_dinv<<<N / 256, 256, 0, stream>>>(deg, dinv, N);
    k_scan<<<1, 1024, 0, stream>>>(cntc, cntr, cptr, rptr, curc, curr, N, E);
    k_scatter<<<E / 256, 256, 0, stream>>>(row, col, ew, E, dinv, curc, curr, colr, coln, rowc, roww);

    // --- level 0 GCN: x0_ = relu(M^T (x0 @ W0_in) + b0_in) ---
    gemm_ab<<<dim3(2, 128), 256, 0, stream>>>(x0, W0_in, h0, 8192, 128, 128, nullptr, 0, 0);
    k_agg<<<N, 128, 0, stream>>>(h0, x0_, cptr, colr, coln, dinv, 128, b0_in, 1);

    // --- s1 = relu((M^T x0_) @ Wp1 + bp1)  (feature-commuted) ---
    k_agg<<<N, 128, 0, stream>>>(x0_, h0 /*=z*/, cptr, colr, coln, dinv, 128, nullptr, 0);
    gemm_ab<<<dim3(16, 128), 256, 0, stream>>>(h0, Wp1, s1o, 8192, 1024, 128, bp1, 1, 0);

    // --- diff_pool level 1 ---
    k_softmax_ent<<<N, 256, 0, stream>>>(s1o, S, 1024, mask, &scal[0]);          // S = softmax(s1)*mask, e1
    k_spmm<<<N, 256, 0, stream>>>(S, rptr, rowc, roww, t, &scal[1]);             // t = A@S, cross term
    gemm_atb<<<dim3(16, 16), 256, 0, stream>>>(S, t, adj1o, 1024, 1024, 8192, nullptr, 0, nullptr, nullptr);  // adj1
    gemm_atb<<<dim3(16, 16), 256, 0, stream>>>(S, S, nullptr, 1024, 1024, 8192, nullptr, 0, nullptr, &scal[2]); // ||S^T S||^2
    gemm_atb<<<dim3(2, 16), 256, 0, stream>>>(S, x0_, x1, 1024, 128, 8192, nullptr, 0, mask, nullptr);        // x1 = S^T (x0_*mask)

    // --- a_norm for adj1 ---
    k_colprep<<<4, 256, 0, stream>>>(adj1o, 1024, di1, df1);
    k_anorm<<<4096, 256, 0, stream>>>(adj1o, 1024, di1, df1, an1);

    // --- level 1 dense GCNs ---
    gemm_ab<<<dim3(2, 16), 256, 0, stream>>>(x1, W1_in, hA, 1024, 128, 128, nullptr, 0, 0);
    gemm_atb<<<dim3(2, 16), 256, 0, stream>>>(an1, hA, x1_, 1024, 128, 1024, b1_in, 1, nullptr, nullptr);
    gemm_ab<<<dim3(2, 16), 256, 0, stream>>>(x1_, Wp2, hB, 1024, 128, 128, nullptr, 0, 0);
    gemm_atb<<<dim3(2, 16), 256, 0, stream>>>(an1, hB, s2, 1024, 128, 1024, bp2, 1, nullptr, nullptr);

    // --- diff_pool level 2 ---
    k_softmax_ent<<<1024, 256, 0, stream>>>(s2, S2s, 128, nullptr, &scal[5]);    // e2
    gemm_ab<<<dim3(2, 16), 256, 0, stream>>>(adj1o, S2s, u, 1024, 128, 1024, nullptr, 0, 0);   // u = adj1 @ S2s
    gemm_atb<<<dim3(2, 2), 256, 0, stream>>>(S2s, x1_, x2, 128, 128, 1024, nullptr, 0, nullptr, nullptr);
    gemm_atb<<<dim3(2, 2), 256, 0, stream>>>(S2s, u, adj2, 128, 128, 1024, nullptr, 0, nullptr, nullptr);
    k_l2<<<1024, 128, 0, stream>>>(adj1o, S2s, &scal[4]);                        // l2 raw sum

    // --- a_norm for adj2, level 2 GCN ---
    k_colprep<<<1, 128, 0, stream>>>(adj2, 128, di2, df2);
    k_anorm<<<64, 256, 0, stream>>>(adj2, 128, di2, df2, an2);
    gemm_ab<<<dim3(2, 2), 256, 0, stream>>>(x2, W2_in, hC, 128, 128, 128, nullptr, 0, 0);
    gemm_atb<<<dim3(2, 2), 256, 0, stream>>>(an2, hC, x2_, 128, 128, 128, b2_in, 1, nullptr, nullptr);

    // --- unpool to level 1 ---
    gemm_ab<<<dim3(2, 16), 256, 0, stream>>>(s2, x2_, x2up, 1024, 128, 128, nullptr, 0, 0);    // s2 (pre-softmax) @ x2_
    gemm_ab<<<dim3(2, 16), 256, 0, stream>>>(x1_, W1_out, hcat, 1024, 128, 128, nullptr, 0, 0);
    gemm_ab<<<dim3(2, 16), 256, 0, stream>>>(x2up, W1_out + 128 * 128, hcat, 1024, 128, 128, nullptr, 0, 1);
    gemm_atb<<<dim3(2, 16), 256, 0, stream>>>(an1, hcat, x1o_, 1024, 128, 1024, b1_out, 1, nullptr, nullptr);

    // --- unpool to level 0, final GCN ---
    gemm_ab<<<dim3(2, 128), 256, 0, stream>>>(s1o, x1o_, x1up, 8192, 128, 1024, nullptr, 0, 0); // s1 @ x1_out
    gemm_ab<<<dim3(1, 128), 256, 0, stream>>>(x0_, W0_out, p16, 8192, 16, 128, nullptr, 0, 0);
    gemm_ab<<<dim3(1, 128), 256, 0, stream>>>(x1up, W0_out + 128 * 16, p16, 8192, 16, 128, nullptr, 0, 1);
    k_agg<<<N, 128, 0, stream>>>(p16, h16, cptr, colr, coln, dinv, 16, b0_out, 1);
    k_logsoftmax<<<32, 256, 0, stream>>>(h16, predo, N);

    // --- edge_loss scalar ---
    k_finalize<<<1, 64, 0, stream>>>(scal, losso);
}

// Round 2
// 2721.829 us; speedup vs baseline: 2.3921x; 2.3921x over previous
//
#include <hip/hip_runtime.h>
#include <math.h>

// ---------------------------------------------------------------------------
// DiffPool GNN (N=8192, E=262144, F=H=128, C1=1024, C2=128, NC=16).
// R2: K=8192 reductions (adj1, ||S^T S||^2, x1) moved to bf16 MFMA split-K.
// ---------------------------------------------------------------------------

#define N_NODES 8192
#define N_EDGES 262144

typedef __attribute__((ext_vector_type(8))) short short8;
typedef __attribute__((ext_vector_type(4))) float floatx4;

// ---------------- workspace layout (float-slot offsets) ----------------
#define OFF_DEG     0           // 8192  (zeroed)
#define OFF_CNTC    8192        // 8192  (zeroed)
#define OFF_CNTR    16384       // 8192  (zeroed)
#define OFF_SCAL    24576       // 16    (zeroed)  [0]=e1 [1]=cross [2]=g2 [3]=sumA2 [4]=l2 [5]=e2
#define ZERO_FLOATS 24592
#define OFF_COLPTR  24592       // 8193
#define OFF_ROWPTR  32785       // 8193
#define OFF_CURC    40978       // 8192
#define OFF_CURR    49170       // 8192
#define OFF_COLR    57362       // E (int)
#define OFF_COLN    319506      // E
#define OFF_ROWC    581650      // E (int)
#define OFF_ROWW    843794      // E
#define OFF_DINV    1105938     // 8192
#define OFF_X0      1114130     // 8192*128 fp32 (x0_, live to the end)
#define OFF_H0      2162706     // 8192*128 fp32 (h0/z; reused as G after s1o gemm)
#define OFF_G       OFF_H0      // 1024*1024 fp32 (G = S^T S)
// Region A (old S region, 8M float-slots): S fp32 lives until transpose-S done.
#define OFF_S       3211282     // 8192*1024 fp32
#define OFF_TT      OFF_S             // T_T bf16 [1024][8192] (after S dead; until adj1 gemm)
#define OFF_AN1     OFF_S             // 1024*1024 fp32 (after adj1 gemm)
#define OFF_X1UP    (OFF_S+1048576)   // 8192*128 fp32
#define OFF_X0T     (OFF_S+4194304)   // bf16 [128][8192] (after S dead)
#define A2          (OFF_S+4718592)
#define OFF_X1      (A2+0)            // 1024*128
#define OFF_HA      (A2+131072)
#define OFF_X1_     (A2+262144)
#define OFF_HB      (A2+393216)
#define OFF_S2      (A2+524288)
#define OFF_S2S     (A2+655360)
#define OFF_U       (A2+786432)
#define OFF_X2      (A2+917504)       // 128*128
#define OFF_ADJ2    (A2+933888)
#define OFF_HC      (A2+950272)
#define OFF_X2_     (A2+966656)
#define OFF_AN2     (A2+983040)
#define OFF_X2UP    (A2+999424)       // 1024*128
#define OFF_HCAT    (A2+1130496)
#define OFF_X1O     (A2+1261568)
#define OFF_P16     (A2+1392640)      // 8192*16
#define OFF_H16     (A2+1523712)
#define OFF_DI1     (A2+1654784)      // 1024
#define OFF_DF1     (A2+1655808)
#define OFF_DI2     (A2+1656832)      // 128
#define OFF_DF2     (A2+1656960)
// Region B (old t region, 8M float-slots):
#define OFF_T       11599890
#define OFF_ST      OFF_T             // S_T bf16 [1024][8192]
#define OFF_TBF     (OFF_T+4194304)   // t bf16 [8192][1024]
// total ws: 19,988,498 float-slots = 76.3 MiB (same as R1)

// ------------------- output layout (floats) -------------------
#define OUT_PRED 0          // 8192*16
#define OUT_S1   131072     // 8192*1024
#define OUT_LOSS 8519680    // 1
#define OUT_ADJ1 8519681    // 1024*1024

__device__ __forceinline__ unsigned short f2bf(float f) {
    union { float f; unsigned u; } v; v.f = f;
    unsigned r = (v.u + 0x7FFF + ((v.u >> 16) & 1)) >> 16;
    return (unsigned short)r;
}

// =========================== graph-structure kernels ===========================

__global__ void k_hist(const int* __restrict__ row, const int* __restrict__ col,
                       const float* __restrict__ ew, int E,
                       float* deg, int* cntc, int* cntr, float* sumA2) {
    __shared__ float red[256];
    int e = blockIdx.x * 256 + threadIdx.x;
    float w2 = 0.f;
    if (e < E) {
        int r = row[e], c = col[e];
        float w = ew[e];
        atomicAdd(&deg[c], w);
        atomicAdd(&cntc[c], 1);
        atomicAdd(&cntr[r], 1);
        w2 = w * w;
    }
    red[threadIdx.x] = w2; __syncthreads();
    for (int s = 128; s > 0; s >>= 1) { if (threadIdx.x < s) red[threadIdx.x] += red[threadIdx.x + s]; __syncthreads(); }
    if (threadIdx.x == 0) atomicAdd(sumA2, red[0]);
}

__global__ void k_dinv(const float* deg, float* dinv, int n) {
    int i = blockIdx.x * 256 + threadIdx.x;
    if (i < n) {
        float d = deg[i] + 1.0f;
        dinv[i] = (d > 0.f) ? 1.0f / sqrtf(d) : 0.f;
    }
}

__global__ __launch_bounds__(1024) void k_scan(const int* cntc, const int* cntr,
        int* colptr, int* rowptr, int* curc, int* curr, int n, int E) {
    __shared__ int part[1024];
    int tid = threadIdx.x;
    const int per = 8;
    for (int pass = 0; pass < 2; ++pass) {
        const int* cnt = pass ? cntr : cntc;
        int* ptr = pass ? rowptr : colptr;
        int* cur = pass ? curr : curc;
        int st = tid * per;
        int loc[per]; int s = 0;
        for (int i = 0; i < per; ++i) { loc[i] = s; s += cnt[st + i]; }
        part[tid] = s; __syncthreads();
        for (int off = 1; off < 1024; off <<= 1) {
            int v = part[tid];
            int add = (tid >= off) ? part[tid - off] : 0;
            __syncthreads();
            part[tid] = v + add;
            __syncthreads();
        }
        int pre = (tid == 0) ? 0 : part[tid - 1];
        for (int i = 0; i < per; ++i) { int v = pre + loc[i]; ptr[st + i] = v; cur[st + i] = v; }
        if (tid == 0) ptr[n] = E;
        __syncthreads();
    }
}

__global__ void k_scatter(const int* __restrict__ row, const int* __restrict__ col,
                          const float* __restrict__ ew, int E, const float* __restrict__ dinv,
                          int* curc, int* curr, int* colr, float* coln, int* rowc, float* roww) {
    int e = blockIdx.x * 256 + threadIdx.x;
    if (e >= E) return;
    int r = row[e], c = col[e];
    float w = ew[e];
    float nrm = dinv[r] * w * dinv[c];
    int p = atomicAdd(&curc[c], 1);
    colr[p] = r; coln[p] = nrm;
    int q = atomicAdd(&curr[r], 1);
    rowc[q] = c; roww[q] = w;
}

// =========================== fp32 GEMMs (mid-size) ===========================

__global__ __launch_bounds__(256) void gemm_ab(const float* __restrict__ A, const float* __restrict__ B,
        float* __restrict__ C, int M, int N, int K,
        const float* __restrict__ bias, int relu, int accum) {
    __shared__ float As[16][68];
    __shared__ float Bs[16][68];
    int tid = threadIdx.x, tx = tid & 15, ty = tid >> 4;
    int m0 = blockIdx.y * 64, n0 = blockIdx.x * 64;
    float acc[4][4] = {};
    for (int k0 = 0; k0 < K; k0 += 16) {
        for (int l = 0; l < 4; ++l) {
            int idx = tid + 256 * l;
            int mm = idx >> 4, kk = idx & 15;
            int m = m0 + mm, k = k0 + kk;
            As[kk][mm] = (m < M && k < K) ? A[(size_t)m * K + k] : 0.f;
            int kk2 = idx >> 6, nn = idx & 63;
            int k2 = k0 + kk2, n = n0 + nn;
            Bs[kk2][nn] = (k2 < K && n < N) ? B[(size_t)k2 * N + n] : 0.f;
        }
        __syncthreads();
        #pragma unroll
        for (int kk = 0; kk < 16; ++kk) {
            float a[4], b[4];
            #pragma unroll
            for (int i = 0; i < 4; ++i) a[i] = As[kk][ty * 4 + i];
            #pragma unroll
            for (int j = 0; j < 4; ++j) b[j] = Bs[kk][tx * 4 + j];
            #pragma unroll
            for (int i = 0; i < 4; ++i)
                #pragma unroll
                for (int j = 0; j < 4; ++j) acc[i][j] += a[i] * b[j];
        }
        __syncthreads();
    }
    for (int i = 0; i < 4; ++i) {
        int m = m0 + ty * 4 + i; if (m >= M) continue;
        for (int j = 0; j < 4; ++j) {
            int n = n0 + tx * 4 + j; if (n >= N) continue;
            float v = acc[i][j];
            if (accum) v += C[(size_t)m * N + n];
            if (bias) v += bias[n];
            if (relu) v = fmaxf(v, 0.f);
            C[(size_t)m * N + n] = v;
        }
    }
}

__global__ __launch_bounds__(256) void gemm_atb(const float* __restrict__ A, const float* __restrict__ B,
        float* __restrict__ C, int M, int N, int K,
        const float* __restrict__ bias, int relu) {
    __shared__ float As[16][68];
    __shared__ float Bs[16][68];
    int tid = threadIdx.x, tx = tid & 15, ty = tid >> 4;
    int m0 = blockIdx.y * 64, n0 = blockIdx.x * 64;
    float acc[4][4] = {};
    for (int k0 = 0; k0 < K; k0 += 16) {
        for (int l = 0; l < 4; ++l) {
            int idx = tid + 256 * l;
            int kk = idx >> 6, mm = idx & 63;
            int k = k0 + kk;
            int m = m0 + mm;
            As[kk][mm] = (k < K && m < M) ? A[(size_t)k * M + m] : 0.f;
            int n = n0 + mm;
            Bs[kk][mm] = (k < K && n < N) ? B[(size_t)k * N + n] : 0.f;
        }
        __syncthreads();
        #pragma unroll
        for (int kk = 0; kk < 16; ++kk) {
            float a[4], b[4];
            #pragma unroll
            for (int i = 0; i < 4; ++i) a[i] = As[kk][ty * 4 + i];
            #pragma unroll
            for (int j = 0; j < 4; ++j) b[j] = Bs[kk][tx * 4 + j];
            #pragma unroll
            for (int i = 0; i < 4; ++i)
                #pragma unroll
                for (int j = 0; j < 4; ++j) acc[i][j] += a[i] * b[j];
        }
        __syncthreads();
    }
    for (int i = 0; i < 4; ++i) {
        int m = m0 + ty * 4 + i; if (m >= M) continue;
        for (int j = 0; j < 4; ++j) {
            int n = n0 + tx * 4 + j; if (n >= N) continue;
            float v = acc[i][j];
            if (bias) v += bias[n];
            if (relu) v = fmaxf(v, 0.f);
            C[(size_t)m * N + n] = v;
        }
    }
}

// =========================== bf16 MFMA GEMM (TN, split-K) ===========================
// C[M][N] += A^T B with A-storage [M][K] bf16 (k contiguous), B-storage [N][K] bf16.
// 128x128 tile, 4 waves (2x2), 16x16x32 mfma, XOR-swizzled LDS, atomicAdd epilogue.
__global__ __launch_bounds__(256) void gemm_tn_bf16(
        const unsigned short* __restrict__ A, const unsigned short* __restrict__ B,
        float* __restrict__ C, int M, int N, int K, int ksplit) {
    __shared__ __align__(16) unsigned short As[128 * 64];
    __shared__ __align__(16) unsigned short Bs[128 * 64];
    int tid = threadIdx.x;
    int wave = tid >> 6, lane = tid & 63;
    int wm = wave >> 1, wn = wave & 1;
    int m0 = blockIdx.x * 128, n0 = blockIdx.y * 128;
    int kchunk = K / ksplit;
    int k0 = blockIdx.z * kchunk;
    floatx4 acc[4][4] = {};
    int sr = tid >> 3;           // 0..31
    int sc = (tid & 7) * 8;      // 0..56
    int q = lane >> 4, lm = lane & 15;
    for (int kt = 0; kt < kchunk; kt += 64) {
        #pragma unroll
        for (int p = 0; p < 4; ++p) {
            int mrow = sr + p * 32;
            int gk = k0 + kt + sc;
            int scs = sc ^ ((mrow & 7) * 8);
            *(short8*)(&As[mrow * 64 + scs]) = *(const short8*)(&A[(size_t)(m0 + mrow) * K + gk]);
            *(short8*)(&Bs[mrow * 64 + scs]) = *(const short8*)(&B[(size_t)(n0 + mrow) * K + gk]);
        }
        __syncthreads();
        #pragma unroll
        for (int ks = 0; ks < 64; ks += 32) {
            short8 af[4], bf[4];
            int kk = ks + q * 8;
            #pragma unroll
            for (int i = 0; i < 4; ++i) {
                int ml = wm * 64 + i * 16 + lm;
                af[i] = *(const short8*)(&As[ml * 64 + (kk ^ ((ml & 7) * 8))]);
                int nl = wn * 64 + i * 16 + lm;
                bf[i] = *(const short8*)(&Bs[nl * 64 + (kk ^ ((nl & 7) * 8))]);
            }
            #pragma unroll
            for (int i = 0; i < 4; ++i)
                #pragma unroll
                for (int j = 0; j < 4; ++j)
                    acc[i][j] = __builtin_amdgcn_mfma_f32_16x16x32_bf16(af[i], bf[j], acc[i][j], 0, 0, 0);
        }
        __syncthreads();
    }
    // C/D layout: col = lane&15, row = (lane>>4)*4 + reg
    for (int i = 0; i < 4; ++i) {
        int rowb = m0 + wm * 64 + i * 16 + q * 4;
        for (int j = 0; j < 4; ++j) {
            int col = n0 + wn * 64 + j * 16 + lm;
            #pragma unroll
            for (int r = 0; r < 4; ++r)
                atomicAdd(&C[(size_t)(rowb + r) * N + col], acc[i][j][r]);
        }
    }
}

// =========================== transposes ===========================

// fp32 in[R][C] -> bf16 out[C][R], optional per-row scale. R,C multiples of 64.
__global__ __launch_bounds__(256) void k_transpose_f2b(
        const float* __restrict__ in, unsigned short* __restrict__ outb,
        int R, int C, const float* __restrict__ rowscale) {
    __shared__ float tile[64][65];
    int rb = blockIdx.y * 64, cb = blockIdx.x * 64;
    int t = threadIdx.x;
    int lr = t >> 4, lc4 = (t & 15) * 4;
    #pragma unroll
    for (int p = 0; p < 4; ++p) {
        int r = rb + lr + p * 16;
        float4 v = *(const float4*)(in + (size_t)r * C + cb + lc4);
        float s = rowscale ? rowscale[r] : 1.0f;
        tile[lr + p * 16][lc4 + 0] = v.x * s;
        tile[lr + p * 16][lc4 + 1] = v.y * s;
        tile[lr + p * 16][lc4 + 2] = v.z * s;
        tile[lr + p * 16][lc4 + 3] = v.w * s;
    }
    __syncthreads();
    int cc0 = t >> 5, rr = (t & 31) * 2;
    #pragma unroll
    for (int p = 0; p < 8; ++p) {
        int cc = cc0 + p * 8;
        unsigned a = f2bf(tile[rr][cc]);
        unsigned b = f2bf(tile[rr + 1][cc]);
        *(unsigned*)(outb + (size_t)(cb + cc) * R + rb + rr) = a | (b << 16);
    }
}

// bf16 in[R][C] -> bf16 out[C][R]. R,C multiples of 64.
__global__ __launch_bounds__(256) void k_transpose_b2b(
        const unsigned short* __restrict__ in, unsigned short* __restrict__ out, int R, int C) {
    __shared__ __align__(16) unsigned short tile[64][72];
    int rb = blockIdx.y * 64, cb = blockIdx.x * 64;
    int t = threadIdx.x;
    int lr = t >> 3, lc = (t & 7) * 8;
    #pragma unroll
    for (int p = 0; p < 2; ++p) {
        int r = lr + p * 32;
        *(short8*)(&tile[r][lc]) = *(const short8*)(&in[(size_t)(rb + r) * C + cb + lc]);
    }
    __syncthreads();
    int cc0 = t >> 4, rr = (t & 15) * 4;
    #pragma unroll
    for (int p = 0; p < 4; ++p) {
        int cc = cc0 + p * 16;
        unsigned long long v = (unsigned long long)tile[rr][cc]
                             | ((unsigned long long)tile[rr + 1][cc] << 16)
                             | ((unsigned long long)tile[rr + 2][cc] << 32)
                             | ((unsigned long long)tile[rr + 3][cc] << 48);
        *(unsigned long long*)(&out[(size_t)(cb + cc) * R + rb + rr]) = v;
    }
}

// =========================== misc kernels ===========================

__global__ void k_agg(const float* __restrict__ h, float* __restrict__ out,
                      const int* __restrict__ cptr, const int* __restrict__ colr,
                      const float* __restrict__ coln, const float* __restrict__ dinv,
                      int F, const float* __restrict__ bias, int relu) {
    int c = blockIdx.x;
    int f = threadIdx.x;
    if (f >= F) return;
    float d = dinv[c];
    float acc = d * d * h[(size_t)c * F + f];
    int e0 = cptr[c], e1 = cptr[c + 1];
    for (int e = e0; e < e1; ++e)
        acc += coln[e] * h[(size_t)colr[e] * F + f];
    if (bias) acc += bias[f];
    if (relu) acc = fmaxf(acc, 0.f);
    out[(size_t)c * F + f] = acc;
}

__global__ __launch_bounds__(256) void k_softmax_ent(const float* __restrict__ x, float* __restrict__ S,
        int W, const float* __restrict__ mask, float* ent_acc) {
    __shared__ float red[256];
    int row = blockIdx.x, tid = threadIdx.x;
    const float* xr = x + (size_t)row * W;
    float m = -3.0e38f;
    for (int q = tid; q < W; q += 256) m = fmaxf(m, xr[q]);
    red[tid] = m; __syncthreads();
    for (int s = 128; s > 0; s >>= 1) { if (tid < s) red[tid] = fmaxf(red[tid], red[tid + s]); __syncthreads(); }
    m = red[0]; __syncthreads();
    float sum = 0.f;
    for (int q = tid; q < W; q += 256) sum += expf(xr[q] - m);
    red[tid] = sum; __syncthreads();
    for (int s = 128; s > 0; s >>= 1) { if (tid < s) red[tid] += red[tid + s]; __syncthreads(); }
    float inv = 1.0f / red[0]; __syncthreads();
    float mk = mask ? mask[row] : 1.0f;
    float* Sr = S + (size_t)row * W;
    float ent = 0.f;
    for (int q = tid; q < W; q += 256) {
        float v = expf(xr[q] - m) * inv * mk;
        Sr[q] = v;
        ent -= v * logf(v + 1e-15f);
    }
    red[tid] = ent; __syncthreads();
    for (int s = 128; s > 0; s >>= 1) { if (tid < s) red[tid] += red[tid + s]; __syncthreads(); }
    if (tid == 0) atomicAdd(ent_acc, red[0]);
}

// t[r,:] = sum_e w_e S[c_e,:] (CSR), written bf16; cross += sum_e w_e <S[r],S[c]>
__global__ __launch_bounds__(256) void k_spmm(const float* __restrict__ S,
        const int* __restrict__ rptr, const int* __restrict__ rowc, const float* __restrict__ roww,
        unsigned short* __restrict__ tb, float* cross_acc) {
    __shared__ float red[256];
    int r = blockIdx.x, tid = threadIdx.x;
    float acc[4] = {0.f, 0.f, 0.f, 0.f};
    float sr[4];
    const float* Srow = S + (size_t)r * 1024;
    #pragma unroll
    for (int j = 0; j < 4; ++j) sr[j] = Srow[tid + 256 * j];
    float lp = 0.f;
    int e0 = rptr[r], e1 = rptr[r + 1];
    for (int e = e0; e < e1; ++e) {
        int c = rowc[e]; float w = roww[e];
        const float* Sc = S + (size_t)c * 1024;
        #pragma unroll
        for (int j = 0; j < 4; ++j) {
            float v = Sc[tid + 256 * j];
            acc[j] += w * v;
            lp += w * sr[j] * v;
        }
    }
    unsigned short* tr = tb + (size_t)r * 1024;
    #pragma unroll
    for (int j = 0; j < 4; ++j) tr[tid + 256 * j] = f2bf(acc[j]);
    red[tid] = lp; __syncthreads();
    for (int s = 128; s > 0; s >>= 1) { if (tid < s) red[tid] += red[tid + s]; __syncthreads(); }
    if (tid == 0) atomicAdd(cross_acc, red[0]);
}

__global__ __launch_bounds__(256) void k_sumsq(const float* __restrict__ g, int n, float* acc) {
    __shared__ float red[256];
    float s = 0.f;
    for (int i = blockIdx.x * 256 + threadIdx.x; i < n; i += gridDim.x * 256) { float v = g[i]; s += v * v; }
    red[threadIdx.x] = s; __syncthreads();
    for (int st = 128; st > 0; st >>= 1) { if (threadIdx.x < st) red[threadIdx.x] += red[threadIdx.x + st]; __syncthreads(); }
    if (threadIdx.x == 0) atomicAdd(acc, red[0]);
}

__global__ void k_colprep(const float* __restrict__ adjm, int n, float* dinvv, float* dfix) {
    int j = blockIdx.x * blockDim.x + threadIdx.x;
    if (j >= n) return;
    float s = 0.f;
    for (int i = 0; i < n; ++i) s += adjm[(size_t)i * n + j];
    float diag = adjm[(size_t)j * n + j];
    float fix = (diag == 0.f) ? 1.0f : 0.f;
    s += fix;
    dfix[j] = fix;
    dinvv[j] = (s > 0.f) ? 1.0f / sqrtf(s) : 0.f;
}

__global__ void k_anorm(const float* __restrict__ adjm, int n, const float* __restrict__ dinvv,
                        const float* __restrict__ dfix, float* __restrict__ anorm) {
    int idx = blockIdx.x * 256 + threadIdx.x;
    if (idx >= n * n) return;
    int i = idx / n, j = idx % n;
    float v = adjm[idx] + ((i == j) ? dfix[j] : 0.f);
    anorm[idx] = dinvv[i] * v * dinvv[j];
}

__global__ __launch_bounds__(128) void k_l2(const float* __restrict__ adjm, const float* __restrict__ S2,
        float* acc) {
    __shared__ float sp[128];
    __shared__ float red[128];
    int p = blockIdx.x, tid = threadIdx.x;
    sp[tid] = S2[(size_t)p * 128 + tid];
    __syncthreads();
    float part = 0.f;
    for (int q = tid; q < 1024; q += 128) {
        const float* Sq = S2 + (size_t)q * 128;
        float dot = 0.f;
        #pragma unroll 8
        for (int k = 0; k < 128; ++k) dot += Sq[k] * sp[k];
        float d = adjm[(size_t)p * 1024 + q] - dot;
        part += d * d;
    }
    red[tid] = part; __syncthreads();
    for (int s = 64; s > 0; s >>= 1) { if (tid < s) red[tid] += red[tid + s]; __syncthreads(); }
    if (tid == 0) atomicAdd(acc, red[0]);
}

__global__ void k_logsoftmax(const float* __restrict__ x, float* __restrict__ out, int n) {
    int i = blockIdx.x * 256 + threadIdx.x;
    if (i >= n) return;
    float v[16];
    float m = -3.0e38f;
    #pragma unroll
    for (int j = 0; j < 16; ++j) { v[j] = x[(size_t)i * 16 + j]; m = fmaxf(m, v[j]); }
    float s = 0.f;
    #pragma unroll
    for (int j = 0; j < 16; ++j) s += expf(v[j] - m);
    float ls = m + logf(s);
    #pragma unroll
    for (int j = 0; j < 16; ++j) out[(size_t)i * 16 + j] = v[j] - ls;
}

__global__ void k_finalize(const float* __restrict__ sc, float* loss) {
    if (threadIdx.x == 0 && blockIdx.x == 0) {
        float e1    = sc[0] / 8192.0f;
        float cross = sc[1];
        float g2    = sc[2];
        float sumA2 = sc[3];
        float l2s   = sc[4];
        float e2    = sc[5] / 1024.0f;
        float l1 = sqrtf(fmaxf(sumA2 - 2.0f * cross + g2, 0.f)) / 67108864.0f;
        float l2 = sqrtf(fmaxf(l2s, 0.f)) / 1048576.0f;
        *loss = l1 + e1 + l2 + e2;
    }
}

// =========================== launcher ===========================

extern "C" void kernel_launch(void* const* d_in, const int* in_sizes, int n_in,
                              void* d_out, int out_size, void* d_ws, size_t ws_size,
                              hipStream_t stream) {
    const int N = N_NODES, E = N_EDGES;
    const float* x0     = (const float*)d_in[0];
    const int*   eidx   = (const int*)d_in[1];
    const float* ew     = (const float*)d_in[2];
    const float* mask   = (const float*)d_in[4];
    const float* W0_in  = (const float*)d_in[5];
    const float* b0_in  = (const float*)d_in[6];
    const float* Wp1    = (const float*)d_in[7];
    const float* bp1    = (const float*)d_in[8];
    const float* W1_in  = (const float*)d_in[9];
    const float* b1_in  = (const float*)d_in[10];
    const float* Wp2    = (const float*)d_in[11];
    const float* bp2    = (const float*)d_in[12];
    const float* W2_in  = (const float*)d_in[13];
    const float* b2_in  = (const float*)d_in[14];
    const float* W1_out = (const float*)d_in[15];
    const float* b1_out = (const float*)d_in[16];
    const float* W0_out = (const float*)d_in[17];
    const float* b0_out = (const float*)d_in[18];

    float* out   = (float*)d_out;
    float* predo = out + OUT_PRED;
    float* s1o   = out + OUT_S1;
    float* losso = out + OUT_LOSS;
    float* adj1o = out + OUT_ADJ1;

    float* wsf = (float*)d_ws;
    int*   wsi = (int*)d_ws;
    float* deg   = wsf + OFF_DEG;
    int*   cntc  = wsi + OFF_CNTC;
    int*   cntr  = wsi + OFF_CNTR;
    float* scal  = wsf + OFF_SCAL;
    int*   cptr  = wsi + OFF_COLPTR;
    int*   rptr  = wsi + OFF_ROWPTR;
    int*   curc  = wsi + OFF_CURC;
    int*   curr  = wsi + OFF_CURR;
    int*   colr  = wsi + OFF_COLR;
    float* coln  = wsf + OFF_COLN;
    int*   rowc  = wsi + OFF_ROWC;
    float* roww  = wsf + OFF_ROWW;
    float* dinv  = wsf + OFF_DINV;
    float* x0_   = wsf + OFF_X0;
    float* h0    = wsf + OFF_H0;
    float* G     = wsf + OFF_G;
    float* S     = wsf + OFF_S;
    unsigned short* TT  = (unsigned short*)(wsf + OFF_TT);
    unsigned short* ST  = (unsigned short*)(wsf + OFF_ST);
    unsigned short* TBF = (unsigned short*)(wsf + OFF_TBF);
    unsigned short* X0T = (unsigned short*)(wsf + OFF_X0T);
    float* an1   = wsf + OFF_AN1;
    float* x1up  = wsf + OFF_X1UP;
    float* x1    = wsf + OFF_X1;
    float* hA    = wsf + OFF_HA;
    float* x1_   = wsf + OFF_X1_;
    float* hB    = wsf + OFF_HB;
    float* s2    = wsf + OFF_S2;
    float* S2s   = wsf + OFF_S2S;
    float* u     = wsf + OFF_U;
    float* x2    = wsf + OFF_X2;
    float* adj2  = wsf + OFF_ADJ2;
    float* hC    = wsf + OFF_HC;
    float* x2_   = wsf + OFF_X2_;
    float* an2   = wsf + OFF_AN2;
    float* x2up  = wsf + OFF_X2UP;
    float* hcat  = wsf + OFF_HCAT;
    float* x1o_  = wsf + OFF_X1O;
    float* p16   = wsf + OFF_P16;
    float* h16   = wsf + OFF_H16;
    float* di1   = wsf + OFF_DI1;
    float* df1   = wsf + OFF_DF1;
    float* di2   = wsf + OFF_DI2;
    float* df2   = wsf + OFF_DF2;

    const int* row = eidx;
    const int* col = eidx + E;

    hipMemsetAsync(wsf, 0, (size_t)ZERO_FLOATS * sizeof(float), stream);

    // --- graph structure ---
    k_hist<<<E / 256, 256, 0, stream>>>(row, col, ew, E, deg, cntc, cntr, &scal[3]);
    k_dinv<<<N / 256, 256, 0, stream>>>(deg, dinv, N);
    k_scan<<<1, 1024, 0, stream>>>(cntc, cntr, cptr, rptr, curc, curr, N, E);
    k_scatter<<<E / 256, 256, 0, stream>>>(row, col, ew, E, dinv, curc, curr, colr, coln, rowc, roww);

    // --- level 0 GCN ---
    gemm_ab<<<dim3(2, 128), 256, 0, stream>>>(x0, W0_in, h0, 8192, 128, 128, nullptr, 0, 0);
    k_agg<<<N, 128, 0, stream>>>(h0, x0_, cptr, colr, coln, dinv, 128, b0_in, 1);

    // --- s1 (feature-commuted) ---
    k_agg<<<N, 128, 0, stream>>>(x0_, h0, cptr, colr, coln, dinv, 128, nullptr, 0);
    gemm_ab<<<dim3(16, 128), 256, 0, stream>>>(h0, Wp1, s1o, 8192, 1024, 128, bp1, 1, 0);

    // --- diff_pool level 1: softmax, spmm, transposes, MFMA gemms ---
    k_softmax_ent<<<N, 256, 0, stream>>>(s1o, S, 1024, mask, &scal[0]);
    k_spmm<<<N, 256, 0, stream>>>(S, rptr, rowc, roww, TBF, &scal[1]);
    k_transpose_f2b<<<dim3(16, 128), 256, 0, stream>>>(S, ST, 8192, 1024, nullptr);   // S_T (S dead after)
    k_transpose_b2b<<<dim3(16, 128), 256, 0, stream>>>(TBF, TT, 8192, 1024);          // T_T into old-S space
    k_transpose_f2b<<<dim3(2, 128), 256, 0, stream>>>(x0_, X0T, 8192, 128, mask);     // X0T = (x0_*mask)^T

    hipMemsetAsync(adj1o, 0, (size_t)1024 * 1024 * sizeof(float), stream);
    hipMemsetAsync(G,     0, (size_t)1024 * 1024 * sizeof(float), stream);
    hipMemsetAsync(x1,    0, (size_t)1024 * 128 * sizeof(float), stream);
    gemm_tn_bf16<<<dim3(8, 8, 8), 256, 0, stream>>>(ST, TT, adj1o, 1024, 1024, 8192, 8);  // adj1 = S^T t
    gemm_tn_bf16<<<dim3(8, 8, 8), 256, 0, stream>>>(ST, ST, G, 1024, 1024, 8192, 8);      // G = S^T S
    gemm_tn_bf16<<<dim3(8, 1, 16), 256, 0, stream>>>(ST, X0T, x1, 1024, 128, 8192, 16);   // x1 = S^T x0m
    k_sumsq<<<256, 256, 0, stream>>>(G, 1024 * 1024, &scal[2]);

    // --- a_norm for adj1 (T_T dead; an1 overwrites it) ---
    k_colprep<<<4, 256, 0, stream>>>(adj1o, 1024, di1, df1);
    k_anorm<<<4096, 256, 0, stream>>>(adj1o, 1024, di1, df1, an1);

    // --- level 1 dense GCNs ---
    gemm_ab<<<dim3(2, 16), 256, 0, stream>>>(x1, W1_in, hA, 1024, 128, 128, nullptr, 0, 0);
    gemm_atb<<<dim3(2, 16), 256, 0, stream>>>(an1, hA, x1_, 1024, 128, 1024, b1_in, 1);
    gemm_ab<<<dim3(2, 16), 256, 0, stream>>>(x1_, Wp2, hB, 1024, 128, 128, nullptr, 0, 0);
    gemm_atb<<<dim3(2, 16), 256, 0, stream>>>(an1, hB, s2, 1024, 128, 1024, bp2, 1);

    // --- diff_pool level 2 ---
    k_softmax_ent<<<1024, 256, 0, stream>>>(s2, S2s, 128, nullptr, &scal[5]);
    gemm_ab<<<dim3(2, 16), 256, 0, stream>>>(adj1o, S2s, u, 1024, 128, 1024, nullptr, 0, 0);
    gemm_atb<<<dim3(2, 2), 256, 0, stream>>>(S2s, x1_, x2, 128, 128, 1024, nullptr, 0);
    gemm_atb<<<dim3(2, 2), 256, 0, stream>>>(S2s, u, adj2, 128, 128, 1024, nullptr, 0);
    k_l2<<<1024, 128, 0, stream>>>(adj1o, S2s, &scal[4]);

    // --- a_norm for adj2, level 2 GCN ---
    k_colprep<<<1, 128, 0, stream>>>(adj2, 128, di2, df2);
    k_anorm<<<64, 256, 0, stream>>>(adj2, 128, di2, df2, an2);
    gemm_ab<<<dim3(2, 2), 256, 0, stream>>>(x2, W2_in, hC, 128, 128, 128, nullptr, 0, 0);
    gemm_atb<<<dim3(2, 2), 256, 0, stream>>>(an2, hC, x2_, 128, 128, 128, b2_in, 1);

    // --- unpool to level 1 ---
    gemm_ab<<<dim3(2, 16), 256, 0, stream>>>(s2, x2_, x2up, 1024, 128, 128, nullptr, 0, 0);
    gemm_ab<<<dim3(2, 16), 256, 0, stream>>>(x1_, W1_out, hcat, 1024, 128, 128, nullptr, 0, 0);
    gemm_ab<<<dim3(2, 16), 256, 0, stream>>>(x2up, W1_out + 128 * 128, hcat, 1024, 128, 128, nullptr, 0, 1);
    gemm_atb<<<dim3(2, 16), 256, 0, stream>>>(an1, hcat, x1o_, 1024, 128, 1024, b1_out, 1);

    // --- unpool to level 0, final GCN ---
    gemm_ab<<<dim3(2, 128), 256, 0, stream>>>(s1o, x1o_, x1up, 8192, 128, 1024, nullptr, 0, 0);
    gemm_ab<<<dim3(1, 128), 256, 0, stream>>>(x0_, W0_out, p16, 8192, 16, 128, nullptr, 0, 0);
    gemm_ab<<<dim3(1, 128), 256, 0, stream>>>(x1up, W0_out + 128 * 16, p16, 8192, 16, 128, nullptr, 0, 1);
    k_agg<<<N, 128, 0, stream>>>(p16, h16, cptr, colr, coln, dinv, 16, b0_out, 1);
    k_logsoftmax<<<32, 256, 0, stream>>>(h16, predo, N);

    k_finalize<<<1, 64, 0, stream>>>(scal, losso);
}

// Round 3
// 1428.445 us; speedup vs baseline: 4.5581x; 1.9054x over previous
//
#include <hip/hip_runtime.h>
#include <math.h>

// ---------------------------------------------------------------------------
// DiffPool GNN (N=8192, E=262144, F=H=128, C1=1024, C2=128, NC=16).
// R3: parallel colsum; s1o via MFMA; x1up/x2up algebraically eliminated;
// 32x32-tile fp32 gemms for the latency-bound mid chain; skinny N=16 gemm.
// ---------------------------------------------------------------------------

#define N_NODES 8192
#define N_EDGES 262144

typedef __attribute__((ext_vector_type(8))) short short8;
typedef __attribute__((ext_vector_type(4))) float floatx4;

// ---------------- workspace layout (float-slot offsets) ----------------
#define OFF_DEG     0           // 8192  (zeroed)
#define OFF_CNTC    8192        // 8192  (zeroed)
#define OFF_CNTR    16384       // 8192  (zeroed)
#define OFF_SCAL    24576       // 16    (zeroed)  [0]=e1 [1]=cross [2]=g2 [3]=sumA2 [4]=l2 [5]=e2
#define ZERO_FLOATS 24592
#define OFF_COLPTR  24592       // 8193
#define OFF_ROWPTR  32785       // 8193
#define OFF_CURC    40978       // 8192 (later: colsum scratch)
#define OFF_CURR    49170       // 8192 (later: colsum scratch)
#define OFF_COLR    57362       // E (int)
#define OFF_COLN    319506      // E
#define OFF_ROWC    581650      // E (int)
#define OFF_ROWW    843794      // E
#define OFF_DINV    1105938     // 8192
#define OFF_X0      1114130     // 8192*128 fp32 (x0_, live to the end)
#define OFF_H0      2162706     // 8192*128 fp32 h0; then h0b bf16; then G fp32
#define OFF_G       OFF_H0
// Region A (old S region): S fp32 until transposes done.
#define OFF_S       3211282     // 8192*1024 fp32
#define OFF_TT      OFF_S             // T_T bf16 [1024][8192]
#define OFF_AN1     OFF_S             // 1024*1024 fp32 (after adj1 gemm consumed TT)
#define OFF_X0T     (OFF_S+4194304)   // bf16 [128][8192]
#define A2          (OFF_S+4718592)
#define OFF_X1      (A2+0)            // 1024*128
#define OFF_HA      (A2+131072)       // 1024*128 (later: y 1024*16)
#define OFF_X1_     (A2+262144)
#define OFF_HB      (A2+393216)
#define OFF_S2      (A2+524288)
#define OFF_S2S     (A2+655360)
#define OFF_U       (A2+786432)
#define OFF_X2      (A2+917504)       // 128*128
#define OFF_ADJ2    (A2+933888)
#define OFF_HC      (A2+950272)
#define OFF_X2_     (A2+966656)
#define OFF_AN2     (A2+983040)
#define OFF_Z2      (A2+999424)       // 128*128
#define OFF_HCAT    (A2+1130496)      // 1024*128
#define OFF_X1O     (A2+1261568)      // 1024*128
#define OFF_P16     (A2+1392640)      // 8192*16
#define OFF_H16     (A2+1523712)
#define OFF_DI1     (A2+1654784)      // 1024
#define OFF_DF1     (A2+1655808)
#define OFF_DI2     (A2+1656832)      // 128
#define OFF_DF2     (A2+1656960)
// Region B (old t region):
#define OFF_T       11599890
#define OFF_ST      OFF_T             // S_T bf16 [1024][8192]
#define OFF_TBF     (OFF_T+4194304)   // t bf16 [8192][1024]; start doubles as Wp1T earlier
#define OFF_WP1T    OFF_TBF           // bf16 [1024][128] (dead before spmm writes TBF)

// ------------------- output layout (floats) -------------------
#define OUT_PRED 0          // 8192*16
#define OUT_S1   131072     // 8192*1024
#define OUT_LOSS 8519680    // 1
#define OUT_ADJ1 8519681    // 1024*1024

__device__ __forceinline__ unsigned short f2bf(float f) {
    union { float f; unsigned u; } v; v.f = f;
    unsigned r = (v.u + 0x7FFF + ((v.u >> 16) & 1)) >> 16;
    return (unsigned short)r;
}

// =========================== graph-structure kernels ===========================

__global__ void k_hist(const int* __restrict__ row, const int* __restrict__ col,
                       const float* __restrict__ ew, int E,
                       float* deg, int* cntc, int* cntr, float* sumA2) {
    __shared__ float red[256];
    int e = blockIdx.x * 256 + threadIdx.x;
    float w2 = 0.f;
    if (e < E) {
        int r = row[e], c = col[e];
        float w = ew[e];
        atomicAdd(&deg[c], w);
        atomicAdd(&cntc[c], 1);
        atomicAdd(&cntr[r], 1);
        w2 = w * w;
    }
    red[threadIdx.x] = w2; __syncthreads();
    for (int s = 128; s > 0; s >>= 1) { if (threadIdx.x < s) red[threadIdx.x] += red[threadIdx.x + s]; __syncthreads(); }
    if (threadIdx.x == 0) atomicAdd(sumA2, red[0]);
}

__global__ void k_dinv(const float* deg, float* dinv, int n) {
    int i = blockIdx.x * 256 + threadIdx.x;
    if (i < n) {
        float d = deg[i] + 1.0f;
        dinv[i] = (d > 0.f) ? 1.0f / sqrtf(d) : 0.f;
    }
}

__global__ __launch_bounds__(1024) void k_scan(const int* cntc, const int* cntr,
        int* colptr, int* rowptr, int* curc, int* curr, int n, int E) {
    __shared__ int part[1024];
    int tid = threadIdx.x;
    const int per = 8;
    for (int pass = 0; pass < 2; ++pass) {
        const int* cnt = pass ? cntr : cntc;
        int* ptr = pass ? rowptr : colptr;
        int* cur = pass ? curr : curc;
        int st = tid * per;
        int loc[per]; int s = 0;
        for (int i = 0; i < per; ++i) { loc[i] = s; s += cnt[st + i]; }
        part[tid] = s; __syncthreads();
        for (int off = 1; off < 1024; off <<= 1) {
            int v = part[tid];
            int add = (tid >= off) ? part[tid - off] : 0;
            __syncthreads();
            part[tid] = v + add;
            __syncthreads();
        }
        int pre = (tid == 0) ? 0 : part[tid - 1];
        for (int i = 0; i < per; ++i) { int v = pre + loc[i]; ptr[st + i] = v; cur[st + i] = v; }
        if (tid == 0) ptr[n] = E;
        __syncthreads();
    }
}

__global__ void k_scatter(const int* __restrict__ row, const int* __restrict__ col,
                          const float* __restrict__ ew, int E, const float* __restrict__ dinv,
                          int* curc, int* curr, int* colr, float* coln, int* rowc, float* roww) {
    int e = blockIdx.x * 256 + threadIdx.x;
    if (e >= E) return;
    int r = row[e], c = col[e];
    float w = ew[e];
    float nrm = dinv[r] * w * dinv[c];
    int p = atomicAdd(&curc[c], 1);
    colr[p] = r; coln[p] = nrm;
    int q = atomicAdd(&curr[r], 1);
    rowc[q] = c; roww[q] = w;
}

// =========================== fp32 GEMMs ===========================

// 64x64 tile (used once: h0 = x0 @ W0_in)
__global__ __launch_bounds__(256) void gemm_ab(const float* __restrict__ A, const float* __restrict__ B,
        float* __restrict__ C, int M, int N, int K) {
    __shared__ float As[16][68];
    __shared__ float Bs[16][68];
    int tid = threadIdx.x, tx = tid & 15, ty = tid >> 4;
    int m0 = blockIdx.y * 64, n0 = blockIdx.x * 64;
    float acc[4][4] = {};
    for (int k0 = 0; k0 < K; k0 += 16) {
        for (int l = 0; l < 4; ++l) {
            int idx = tid + 256 * l;
            int mm = idx >> 4, kk = idx & 15;
            As[kk][mm] = A[(size_t)(m0 + mm) * K + k0 + kk];
            int kk2 = idx >> 6, nn = idx & 63;
            Bs[kk2][nn] = B[(size_t)(k0 + kk2) * N + n0 + nn];
        }
        __syncthreads();
        #pragma unroll
        for (int kk = 0; kk < 16; ++kk) {
            float a[4], b[4];
            #pragma unroll
            for (int i = 0; i < 4; ++i) a[i] = As[kk][ty * 4 + i];
            #pragma unroll
            for (int j = 0; j < 4; ++j) b[j] = Bs[kk][tx * 4 + j];
            #pragma unroll
            for (int i = 0; i < 4; ++i)
                #pragma unroll
                for (int j = 0; j < 4; ++j) acc[i][j] += a[i] * b[j];
        }
        __syncthreads();
    }
    for (int i = 0; i < 4; ++i)
        for (int j = 0; j < 4; ++j)
            C[(size_t)(m0 + ty * 4 + i) * N + n0 + tx * 4 + j] = acc[i][j];
}

// 32x32 tile, C = A@B (+bias/relu/accum). Dims multiples of 32.
__global__ __launch_bounds__(256) void gemm_ab32(const float* __restrict__ A, const float* __restrict__ B,
        float* __restrict__ C, int M, int N, int K,
        const float* __restrict__ bias, int relu, int accum) {
    __shared__ float As[32][33];
    __shared__ float Bs[32][33];
    int tid = threadIdx.x, tx = tid & 15, ty = tid >> 4;
    int m0 = blockIdx.y * 32, n0 = blockIdx.x * 32;
    float acc[2][2] = {};
    for (int k0 = 0; k0 < K; k0 += 32) {
        #pragma unroll
        for (int l = 0; l < 4; ++l) {
            int idx = tid + 256 * l;
            int r = idx >> 5, c = idx & 31;
            As[r][c] = A[(size_t)(m0 + r) * K + k0 + c];
            Bs[r][c] = B[(size_t)(k0 + r) * N + n0 + c];
        }
        __syncthreads();
        #pragma unroll
        for (int kk = 0; kk < 32; ++kk) {
            float a0 = As[ty * 2][kk], a1 = As[ty * 2 + 1][kk];
            float b0 = Bs[kk][tx * 2], b1 = Bs[kk][tx * 2 + 1];
            acc[0][0] += a0 * b0; acc[0][1] += a0 * b1;
            acc[1][0] += a1 * b0; acc[1][1] += a1 * b1;
        }
        __syncthreads();
    }
    #pragma unroll
    for (int i = 0; i < 2; ++i)
        #pragma unroll
        for (int j = 0; j < 2; ++j) {
            int m = m0 + ty * 2 + i, n = n0 + tx * 2 + j;
            float v = acc[i][j];
            if (accum) v += C[(size_t)m * N + n];
            if (bias) v += bias[n];
            if (relu) v = fmaxf(v, 0.f);
            C[(size_t)m * N + n] = v;
        }
}

// 32x32 tile, C = A^T@B with A[K][M], B[K][N].
__global__ __launch_bounds__(256) void gemm_atb32(const float* __restrict__ A, const float* __restrict__ B,
        float* __restrict__ C, int M, int N, int K,
        const float* __restrict__ bias, int relu) {
    __shared__ float As[32][33];
    __shared__ float Bs[32][33];
    int tid = threadIdx.x, tx = tid & 15, ty = tid >> 4;
    int m0 = blockIdx.y * 32, n0 = blockIdx.x * 32;
    float acc[2][2] = {};
    for (int k0 = 0; k0 < K; k0 += 32) {
        #pragma unroll
        for (int l = 0; l < 4; ++l) {
            int idx = tid + 256 * l;
            int r = idx >> 5, c = idx & 31;   // r = k-local, c = m/n-local
            As[c][r] = A[(size_t)(k0 + r) * M + m0 + c];
            Bs[r][c] = B[(size_t)(k0 + r) * N + n0 + c];
        }
        __syncthreads();
        #pragma unroll
        for (int kk = 0; kk < 32; ++kk) {
            float a0 = As[ty * 2][kk], a1 = As[ty * 2 + 1][kk];
            float b0 = Bs[kk][tx * 2], b1 = Bs[kk][tx * 2 + 1];
            acc[0][0] += a0 * b0; acc[0][1] += a0 * b1;
            acc[1][0] += a1 * b0; acc[1][1] += a1 * b1;
        }
        __syncthreads();
    }
    #pragma unroll
    for (int i = 0; i < 2; ++i)
        #pragma unroll
        for (int j = 0; j < 2; ++j) {
            int m = m0 + ty * 2 + i, n = n0 + tx * 2 + j;
            float v = acc[i][j];
            if (bias) v += bias[n];
            if (relu) v = fmaxf(v, 0.f);
            C[(size_t)m * N + n] = v;
        }
}

// C[M][16] (+)= A[M][K] @ B[K][16].  K multiple of 64, M multiple of 16.
__global__ __launch_bounds__(256) void k_gemm_n16(const float* __restrict__ A, const float* __restrict__ B,
        float* __restrict__ C, int M, int K, int accum) {
    __shared__ float As[16][64];
    __shared__ float Bs[64][16];
    int tid = threadIdx.x;
    int r = tid >> 4, c = tid & 15;
    int m0 = blockIdx.x * 16;
    float acc = 0.f;
    for (int k0 = 0; k0 < K; k0 += 64) {
        #pragma unroll
        for (int l = 0; l < 4; ++l) {
            int idx = tid + 256 * l;
            int rr = idx >> 6, cc = idx & 63;
            As[rr][cc] = A[(size_t)(m0 + rr) * K + k0 + cc];
            int kk = idx >> 4, c2 = idx & 15;
            Bs[kk][c2] = B[(size_t)(k0 + kk) * 16 + c2];
        }
        __syncthreads();
        #pragma unroll 16
        for (int kk = 0; kk < 64; ++kk) acc += As[r][kk] * Bs[kk][c];
        __syncthreads();
    }
    float* p = &C[(size_t)(m0 + r) * 16 + c];
    if (accum) acc += *p;
    *p = acc;
}

// =========================== bf16 MFMA GEMMs ===========================
// core: C[m][n] = sum_k A[m*K+k]*B[n*K+k], 128x128 tile, 16x16x32 mfma.

// split-K atomic accumulate version
__global__ __launch_bounds__(256) void gemm_tn_bf16(
        const unsigned short* __restrict__ A, const unsigned short* __restrict__ B,
        float* __restrict__ C, int M, int N, int K, int ksplit) {
    __shared__ __align__(16) unsigned short As[128 * 64];
    __shared__ __align__(16) unsigned short Bs[128 * 64];
    int tid = threadIdx.x;
    int wave = tid >> 6, lane = tid & 63;
    int wm = wave >> 1, wn = wave & 1;
    int m0 = blockIdx.x * 128, n0 = blockIdx.y * 128;
    int kchunk = K / ksplit;
    int k0 = blockIdx.z * kchunk;
    floatx4 acc[4][4] = {};
    int sr = tid >> 3;
    int sc = (tid & 7) * 8;
    int q = lane >> 4, lm = lane & 15;
    for (int kt = 0; kt < kchunk; kt += 64) {
        #pragma unroll
        for (int p = 0; p < 4; ++p) {
            int mrow = sr + p * 32;
            int gk = k0 + kt + sc;
            int scs = sc ^ ((mrow & 7) * 8);
            *(short8*)(&As[mrow * 64 + scs]) = *(const short8*)(&A[(size_t)(m0 + mrow) * K + gk]);
            *(short8*)(&Bs[mrow * 64 + scs]) = *(const short8*)(&B[(size_t)(n0 + mrow) * K + gk]);
        }
        __syncthreads();
        #pragma unroll
        for (int ks = 0; ks < 64; ks += 32) {
            short8 af[4], bf[4];
            int kk = ks + q * 8;
            #pragma unroll
            for (int i = 0; i < 4; ++i) {
                int ml = wm * 64 + i * 16 + lm;
                af[i] = *(const short8*)(&As[ml * 64 + (kk ^ ((ml & 7) * 8))]);
                int nl = wn * 64 + i * 16 + lm;
                bf[i] = *(const short8*)(&Bs[nl * 64 + (kk ^ ((nl & 7) * 8))]);
            }
            #pragma unroll
            for (int i = 0; i < 4; ++i)
                #pragma unroll
                for (int j = 0; j < 4; ++j)
                    acc[i][j] = __builtin_amdgcn_mfma_f32_16x16x32_bf16(af[i], bf[j], acc[i][j], 0, 0, 0);
        }
        __syncthreads();
    }
    for (int i = 0; i < 4; ++i) {
        int rowb = m0 + wm * 64 + i * 16 + q * 4;
        for (int j = 0; j < 4; ++j) {
            int col = n0 + wn * 64 + j * 16 + lm;
            #pragma unroll
            for (int r = 0; r < 4; ++r)
                atomicAdd(&C[(size_t)(rowb + r) * N + col], acc[i][j][r]);
        }
    }
}

// full-K store version with bias+relu (for s1o)
__global__ __launch_bounds__(256) void gemm_tn_bf16_store(
        const unsigned short* __restrict__ A, const unsigned short* __restrict__ B,
        float* __restrict__ C, int M, int N, int K,
        const float* __restrict__ bias, int relu) {
    __shared__ __align__(16) unsigned short As[128 * 64];
    __shared__ __align__(16) unsigned short Bs[128 * 64];
    int tid = threadIdx.x;
    int wave = tid >> 6, lane = tid & 63;
    int wm = wave >> 1, wn = wave & 1;
    int m0 = blockIdx.x * 128, n0 = blockIdx.y * 128;
    floatx4 acc[4][4] = {};
    int sr = tid >> 3;
    int sc = (tid & 7) * 8;
    int q = lane >> 4, lm = lane & 15;
    for (int kt = 0; kt < K; kt += 64) {
        #pragma unroll
        for (int p = 0; p < 4; ++p) {
            int mrow = sr + p * 32;
            int gk = kt + sc;
            int scs = sc ^ ((mrow & 7) * 8);
            *(short8*)(&As[mrow * 64 + scs]) = *(const short8*)(&A[(size_t)(m0 + mrow) * K + gk]);
            *(short8*)(&Bs[mrow * 64 + scs]) = *(const short8*)(&B[(size_t)(n0 + mrow) * K + gk]);
        }
        __syncthreads();
        #pragma unroll
        for (int ks = 0; ks < 64; ks += 32) {
            short8 af[4], bf[4];
            int kk = ks + q * 8;
            #pragma unroll
            for (int i = 0; i < 4; ++i) {
                int ml = wm * 64 + i * 16 + lm;
                af[i] = *(const short8*)(&As[ml * 64 + (kk ^ ((ml & 7) * 8))]);
                int nl = wn * 64 + i * 16 + lm;
                bf[i] = *(const short8*)(&Bs[nl * 64 + (kk ^ ((nl & 7) * 8))]);
            }
            #pragma unroll
            for (int i = 0; i < 4; ++i)
                #pragma unroll
                for (int j = 0; j < 4; ++j)
                    acc[i][j] = __builtin_amdgcn_mfma_f32_16x16x32_bf16(af[i], bf[j], acc[i][j], 0, 0, 0);
        }
        __syncthreads();
    }
    for (int i = 0; i < 4; ++i) {
        int rowb = m0 + wm * 64 + i * 16 + q * 4;
        for (int j = 0; j < 4; ++j) {
            int col = n0 + wn * 64 + j * 16 + lm;
            float bv = bias ? bias[col] : 0.f;
            #pragma unroll
            for (int r = 0; r < 4; ++r) {
                float v = acc[i][j][r] + bv;
                if (relu) v = fmaxf(v, 0.f);
                C[(size_t)(rowb + r) * N + col] = v;
            }
        }
    }
}

// =========================== transposes ===========================

__global__ __launch_bounds__(256) void k_transpose_f2b(
        const float* __restrict__ in, unsigned short* __restrict__ outb,
        int R, int C, const float* __restrict__ rowscale) {
    __shared__ float tile[64][65];
    int rb = blockIdx.y * 64, cb = blockIdx.x * 64;
    int t = threadIdx.x;
    int lr = t >> 4, lc4 = (t & 15) * 4;
    #pragma unroll
    for (int p = 0; p < 4; ++p) {
        int r = rb + lr + p * 16;
        float4 v = *(const float4*)(in + (size_t)r * C + cb + lc4);
        float s = rowscale ? rowscale[r] : 1.0f;
        tile[lr + p * 16][lc4 + 0] = v.x * s;
        tile[lr + p * 16][lc4 + 1] = v.y * s;
        tile[lr + p * 16][lc4 + 2] = v.z * s;
        tile[lr + p * 16][lc4 + 3] = v.w * s;
    }
    __syncthreads();
    int cc0 = t >> 5, rr = (t & 31) * 2;
    #pragma unroll
    for (int p = 0; p < 8; ++p) {
        int cc = cc0 + p * 8;
        unsigned a = f2bf(tile[rr][cc]);
        unsigned b = f2bf(tile[rr + 1][cc]);
        *(unsigned*)(outb + (size_t)(cb + cc) * R + rb + rr) = a | (b << 16);
    }
}

__global__ __launch_bounds__(256) void k_transpose_b2b(
        const unsigned short* __restrict__ in, unsigned short* __restrict__ out, int R, int C) {
    __shared__ __align__(16) unsigned short tile[64][72];
    int rb = blockIdx.y * 64, cb = blockIdx.x * 64;
    int t = threadIdx.x;
    int lr = t >> 3, lc = (t & 7) * 8;
    #pragma unroll
    for (int p = 0; p < 2; ++p) {
        int r = lr + p * 32;
        *(short8*)(&tile[r][lc]) = *(const short8*)(&in[(size_t)(rb + r) * C + cb + lc]);
    }
    __syncthreads();
    int cc0 = t >> 4, rr = (t & 15) * 4;
    #pragma unroll
    for (int p = 0; p < 4; ++p) {
        int cc = cc0 + p * 16;
        unsigned long long v = (unsigned long long)tile[rr][cc]
                             | ((unsigned long long)tile[rr + 1][cc] << 16)
                             | ((unsigned long long)tile[rr + 2][cc] << 32)
                             | ((unsigned long long)tile[rr + 3][cc] << 48);
        *(unsigned long long*)(&out[(size_t)(cb + cc) * R + rb + rr]) = v;
    }
}

// =========================== aggregation / misc ===========================

// GCN sparse aggregation at target c (CSC), self-loop, bias/relu; fp32 or bf16 out.
__global__ void k_agg(const float* __restrict__ h, float* __restrict__ out,
                      unsigned short* __restrict__ outb,
                      const int* __restrict__ cptr, const int* __restrict__ colr,
                      const float* __restrict__ coln, const float* __restrict__ dinv,
                      int F, const float* __restrict__ bias, int relu) {
    int c = blockIdx.x;
    int f = threadIdx.x;
    if (f >= F) return;
    float d = dinv[c];
    float acc = d * d * h[(size_t)c * F + f];
    int e0 = cptr[c], e1 = cptr[c + 1];
    for (int e = e0; e < e1; ++e)
        acc += coln[e] * h[(size_t)colr[e] * F + f];
    if (bias) acc += bias[f];
    if (relu) acc = fmaxf(acc, 0.f);
    if (outb) outb[(size_t)c * F + f] = f2bf(acc);
    else      out[(size_t)c * F + f] = acc;
}

// F=16 variant: 16 nodes per block.
__global__ __launch_bounds__(256) void k_agg16(const float* __restrict__ h, float* __restrict__ out,
        const int* __restrict__ cptr, const int* __restrict__ colr,
        const float* __restrict__ coln, const float* __restrict__ dinv,
        const float* __restrict__ bias) {
    int node = blockIdx.x * 16 + (threadIdx.x >> 4);
    int f = threadIdx.x & 15;
    float d = dinv[node];
    float acc = d * d * h[(size_t)node * 16 + f];
    int e0 = cptr[node], e1 = cptr[node + 1];
    for (int e = e0; e < e1; ++e)
        acc += coln[e] * h[(size_t)colr[e] * 16 + f];
    acc += bias[f];
    out[(size_t)node * 16 + f] = fmaxf(acc, 0.f);
}

__global__ __launch_bounds__(256) void k_softmax_ent(const float* __restrict__ x, float* __restrict__ S,
        int W, const float* __restrict__ mask, float* ent_acc) {
    __shared__ float red[256];
    int row = blockIdx.x, tid = threadIdx.x;
    const float* xr = x + (size_t)row * W;
    float m = -3.0e38f;
    for (int q = tid; q < W; q += 256) m = fmaxf(m, xr[q]);
    red[tid] = m; __syncthreads();
    for (int s = 128; s > 0; s >>= 1) { if (tid < s) red[tid] = fmaxf(red[tid], red[tid + s]); __syncthreads(); }
    m = red[0]; __syncthreads();
    float sum = 0.f;
    for (int q = tid; q < W; q += 256) sum += expf(xr[q] - m);
    red[tid] = sum; __syncthreads();
    for (int s = 128; s > 0; s >>= 1) { if (tid < s) red[tid] += red[tid + s]; __syncthreads(); }
    float inv = 1.0f / red[0]; __syncthreads();
    float mk = mask ? mask[row] : 1.0f;
    float* Sr = S + (size_t)row * W;
    float ent = 0.f;
    for (int q = tid; q < W; q += 256) {
        float v = expf(xr[q] - m) * inv * mk;
        Sr[q] = v;
        ent -= v * logf(v + 1e-15f);
    }
    red[tid] = ent; __syncthreads();
    for (int s = 128; s > 0; s >>= 1) { if (tid < s) red[tid] += red[tid + s]; __syncthreads(); }
    if (tid == 0) atomicAdd(ent_acc, red[0]);
}

__global__ __launch_bounds__(256) void k_spmm(const float* __restrict__ S,
        const int* __restrict__ rptr, const int* __restrict__ rowc, const float* __restrict__ roww,
        unsigned short* __restrict__ tb, float* cross_acc) {
    __shared__ float red[256];
    int r = blockIdx.x, tid = threadIdx.x;
    float acc[4] = {0.f, 0.f, 0.f, 0.f};
    float sr[4];
    const float* Srow = S + (size_t)r * 1024;
    #pragma unroll
    for (int j = 0; j < 4; ++j) sr[j] = Srow[tid + 256 * j];
    float lp = 0.f;
    int e0 = rptr[r], e1 = rptr[r + 1];
    for (int e = e0; e < e1; ++e) {
        int c = rowc[e]; float w = roww[e];
        const float* Sc = S + (size_t)c * 1024;
        #pragma unroll
        for (int j = 0; j < 4; ++j) {
            float v = Sc[tid + 256 * j];
            acc[j] += w * v;
            lp += w * sr[j] * v;
        }
    }
    unsigned short* tr = tb + (size_t)r * 1024;
    #pragma unroll
    for (int j = 0; j < 4; ++j) tr[tid + 256 * j] = f2bf(acc[j]);
    red[tid] = lp; __syncthreads();
    for (int s = 128; s > 0; s >>= 1) { if (tid < s) red[tid] += red[tid + s]; __syncthreads(); }
    if (tid == 0) atomicAdd(cross_acc, red[0]);
}

__global__ __launch_bounds__(256) void k_sumsq(const float* __restrict__ g, int n, float* acc) {
    __shared__ float red[256];
    float s = 0.f;
    for (int i = blockIdx.x * 256 + threadIdx.x; i < n; i += gridDim.x * 256) { float v = g[i]; s += v * v; }
    red[threadIdx.x] = s; __syncthreads();
    for (int st = 128; st > 0; st >>= 1) { if (threadIdx.x < st) red[threadIdx.x] += red[threadIdx.x + st]; __syncthreads(); }
    if (threadIdx.x == 0) atomicAdd(acc, red[0]);
}

// parallel column sum: grid (ceil(n/blockDim), n/64); coalesced rows, atomic per col
__global__ void k_colsum(const float* __restrict__ adjm, int n, float* colsum) {
    int j = blockIdx.x * blockDim.x + threadIdx.x;
    if (j >= n) return;
    int r0 = blockIdx.y * 64;
    float s = 0.f;
    for (int r = r0; r < r0 + 64; ++r) s += adjm[(size_t)r * n + j];
    atomicAdd(&colsum[j], s);
}

__global__ void k_dfix(const float* __restrict__ adjm, int n, const float* __restrict__ colsum,
                       float* dinvv, float* dfix) {
    int j = blockIdx.x * blockDim.x + threadIdx.x;
    if (j >= n) return;
    float diag = adjm[(size_t)j * n + j];
    float fix = (diag == 0.f) ? 1.0f : 0.f;
    float s = colsum[j] + fix;
    dfix[j] = fix;
    dinvv[j] = (s > 0.f) ? 1.0f / sqrtf(s) : 0.f;
}

__global__ void k_anorm(const float* __restrict__ adjm, int n, const float* __restrict__ dinvv,
                        const float* __restrict__ dfix, float* __restrict__ anorm) {
    int idx = blockIdx.x * 256 + threadIdx.x;
    if (idx >= n * n) return;
    int i = idx / n, j = idx % n;
    float v = adjm[idx] + ((i == j) ? dfix[j] : 0.f);
    anorm[idx] = dinvv[i] * v * dinvv[j];
}

__global__ __launch_bounds__(128) void k_l2(const float* __restrict__ adjm, const float* __restrict__ S2,
        float* acc) {
    __shared__ float sp[128];
    __shared__ float red[128];
    int p = blockIdx.x, tid = threadIdx.x;
    sp[tid] = S2[(size_t)p * 128 + tid];
    __syncthreads();
    float part = 0.f;
    for (int q = tid; q < 1024; q += 128) {
        const float* Sq = S2 + (size_t)q * 128;
        float dot = 0.f;
        #pragma unroll 8
        for (int k = 0; k < 128; ++k) dot += Sq[k] * sp[k];
        float d = adjm[(size_t)p * 1024 + q] - dot;
        part += d * d;
    }
    red[tid] = part; __syncthreads();
    for (int s = 64; s > 0; s >>= 1) { if (tid < s) red[tid] += red[tid + s]; __syncthreads(); }
    if (tid == 0) atomicAdd(acc, red[0]);
}

__global__ void k_logsoftmax(const float* __restrict__ x, float* __restrict__ out, int n) {
    int i = blockIdx.x * 256 + threadIdx.x;
    if (i >= n) return;
    float v[16];
    float m = -3.0e38f;
    #pragma unroll
    for (int j = 0; j < 16; ++j) { v[j] = x[(size_t)i * 16 + j]; m = fmaxf(m, v[j]); }
    float s = 0.f;
    #pragma unroll
    for (int j = 0; j < 16; ++j) s += expf(v[j] - m);
    float ls = m + logf(s);
    #pragma unroll
    for (int j = 0; j < 16; ++j) out[(size_t)i * 16 + j] = v[j] - ls;
}

__global__ void k_finalize(const float* __restrict__ sc, float* loss) {
    if (threadIdx.x == 0 && blockIdx.x == 0) {
        float e1    = sc[0] / 8192.0f;
        float cross = sc[1];
        float g2    = sc[2];
        float sumA2 = sc[3];
        float l2s   = sc[4];
        float e2    = sc[5] / 1024.0f;
        float l1 = sqrtf(fmaxf(sumA2 - 2.0f * cross + g2, 0.f)) / 67108864.0f;
        float l2 = sqrtf(fmaxf(l2s, 0.f)) / 1048576.0f;
        *loss = l1 + e1 + l2 + e2;
    }
}

// =========================== launcher ===========================

extern "C" void kernel_launch(void* const* d_in, const int* in_sizes, int n_in,
                              void* d_out, int out_size, void* d_ws, size_t ws_size,
                              hipStream_t stream) {
    const int N = N_NODES, E = N_EDGES;
    const float* x0     = (const float*)d_in[0];
    const int*   eidx   = (const int*)d_in[1];
    const float* ew     = (const float*)d_in[2];
    const float* mask   = (const float*)d_in[4];
    const float* W0_in  = (const float*)d_in[5];
    const float* b0_in  = (const float*)d_in[6];
    const float* Wp1    = (const float*)d_in[7];
    const float* bp1    = (const float*)d_in[8];
    const float* W1_in  = (const float*)d_in[9];
    const float* b1_in  = (const float*)d_in[10];
    const float* Wp2    = (const float*)d_in[11];
    const float* bp2    = (const float*)d_in[12];
    const float* W2_in  = (const float*)d_in[13];
    const float* b2_in  = (const float*)d_in[14];
    const float* W1_out = (const float*)d_in[15];
    const float* b1_out = (const float*)d_in[16];
    const float* W0_out = (const float*)d_in[17];
    const float* b0_out = (const float*)d_in[18];

    float* out   = (float*)d_out;
    float* predo = out + OUT_PRED;
    float* s1o   = out + OUT_S1;
    float* losso = out + OUT_LOSS;
    float* adj1o = out + OUT_ADJ1;

    float* wsf = (float*)d_ws;
    int*   wsi = (int*)d_ws;
    float* deg   = wsf + OFF_DEG;
    int*   cntc  = wsi + OFF_CNTC;
    int*   cntr  = wsi + OFF_CNTR;
    float* scal  = wsf + OFF_SCAL;
    int*   cptr  = wsi + OFF_COLPTR;
    int*   rptr  = wsi + OFF_ROWPTR;
    int*   curc  = wsi + OFF_CURC;
    int*   curr  = wsi + OFF_CURR;
    int*   colr  = wsi + OFF_COLR;
    float* coln  = wsf + OFF_COLN;
    int*   rowc  = wsi + OFF_ROWC;
    float* roww  = wsf + OFF_ROWW;
    float* dinv  = wsf + OFF_DINV;
    float* x0_   = wsf + OFF_X0;
    float* h0    = wsf + OFF_H0;
    unsigned short* h0b = (unsigned short*)(wsf + OFF_H0);
    float* G     = wsf + OFF_G;
    float* S     = wsf + OFF_S;
    unsigned short* TT   = (unsigned short*)(wsf + OFF_TT);
    unsigned short* ST   = (unsigned short*)(wsf + OFF_ST);
    unsigned short* TBF  = (unsigned short*)(wsf + OFF_TBF);
    unsigned short* WP1T = (unsigned short*)(wsf + OFF_WP1T);
    unsigned short* X0T  = (unsigned short*)(wsf + OFF_X0T);
    float* an1   = wsf + OFF_AN1;
    float* x1    = wsf + OFF_X1;
    float* hA    = wsf + OFF_HA;    // reused later as y[1024][16]
    float* x1_   = wsf + OFF_X1_;
    float* hB    = wsf + OFF_HB;
    float* s2    = wsf + OFF_S2;
    float* S2s   = wsf + OFF_S2S;
    float* u     = wsf + OFF_U;
    float* x2    = wsf + OFF_X2;
    float* adj2  = wsf + OFF_ADJ2;
    float* hC    = wsf + OFF_HC;
    float* x2_   = wsf + OFF_X2_;
    float* an2   = wsf + OFF_AN2;
    float* z2    = wsf + OFF_Z2;
    float* hcat  = wsf + OFF_HCAT;
    float* x1o_  = wsf + OFF_X1O;
    float* p16   = wsf + OFF_P16;
    float* h16   = wsf + OFF_H16;
    float* di1   = wsf + OFF_DI1;
    float* df1   = wsf + OFF_DF1;
    float* di2   = wsf + OFF_DI2;
    float* df2   = wsf + OFF_DF2;

    const int* row = eidx;
    const int* col = eidx + E;

    hipMemsetAsync(wsf, 0, (size_t)ZERO_FLOATS * sizeof(float), stream);

    // --- graph structure ---
    k_hist<<<E / 256, 256, 0, stream>>>(row, col, ew, E, deg, cntc, cntr, &scal[3]);
    k_dinv<<<N / 256, 256, 0, stream>>>(deg, dinv, N);
    k_scan<<<1, 1024, 0, stream>>>(cntc, cntr, cptr, rptr, curc, curr, N, E);
    k_scatter<<<E / 256, 256, 0, stream>>>(row, col, ew, E, dinv, curc, curr, colr, coln, rowc, roww);

    // --- level 0 GCN ---
    gemm_ab<<<dim3(2, 128), 256, 0, stream>>>(x0, W0_in, h0, 8192, 128, 128);
    k_agg<<<N, 128, 0, stream>>>(h0, x0_, nullptr, cptr, colr, coln, dinv, 128, b0_in, 1);

    // --- s1 = relu((M^T x0_) @ Wp1 + bp1), z in bf16, MFMA gemm ---
    k_agg<<<N, 128, 0, stream>>>(x0_, nullptr, h0b, cptr, colr, coln, dinv, 128, nullptr, 0);
    k_transpose_f2b<<<dim3(16, 2), 256, 0, stream>>>(Wp1, WP1T, 128, 1024, nullptr);
    gemm_tn_bf16_store<<<dim3(64, 8), 256, 0, stream>>>(h0b, WP1T, s1o, 8192, 1024, 128, bp1, 1);

    // --- diff_pool level 1 ---
    k_softmax_ent<<<N, 256, 0, stream>>>(s1o, S, 1024, mask, &scal[0]);
    k_spmm<<<N, 256, 0, stream>>>(S, rptr, rowc, roww, TBF, &scal[1]);
    k_transpose_f2b<<<dim3(16, 128), 256, 0, stream>>>(S, ST, 8192, 1024, nullptr);
    k_transpose_b2b<<<dim3(16, 128), 256, 0, stream>>>(TBF, TT, 8192, 1024);
    k_transpose_f2b<<<dim3(2, 128), 256, 0, stream>>>(x0_, X0T, 8192, 128, mask);

    hipMemsetAsync(adj1o, 0, (size_t)1024 * 1024 * sizeof(float), stream);
    hipMemsetAsync(G,     0, (size_t)1024 * 1024 * sizeof(float), stream);
    hipMemsetAsync(x1,    0, (size_t)1024 * 128 * sizeof(float), stream);
    gemm_tn_bf16<<<dim3(8, 8, 8), 256, 0, stream>>>(ST, TT, adj1o, 1024, 1024, 8192, 8);
    gemm_tn_bf16<<<dim3(8, 8, 8), 256, 0, stream>>>(ST, ST, G, 1024, 1024, 8192, 8);
    gemm_tn_bf16<<<dim3(8, 1, 16), 256, 0, stream>>>(ST, X0T, x1, 1024, 128, 8192, 16);
    k_sumsq<<<256, 256, 0, stream>>>(G, 1024 * 1024, &scal[2]);

    // --- a_norm for adj1 (parallel colsum; curc reused as scratch) ---
    hipMemsetAsync(curc, 0, 1024 * sizeof(float), stream);
    k_colsum<<<dim3(4, 16), 256, 0, stream>>>(adj1o, 1024, (float*)curc);
    k_dfix<<<4, 256, 0, stream>>>(adj1o, 1024, (float*)curc, di1, df1);
    k_anorm<<<4096, 256, 0, stream>>>(adj1o, 1024, di1, df1, an1);

    // --- level 1 dense GCNs (32-tile) ---
    gemm_ab32<<<dim3(4, 32), 256, 0, stream>>>(x1, W1_in, hA, 1024, 128, 128, nullptr, 0, 0);
    gemm_atb32<<<dim3(4, 32), 256, 0, stream>>>(an1, hA, x1_, 1024, 128, 1024, b1_in, 1);
    gemm_ab32<<<dim3(4, 32), 256, 0, stream>>>(x1_, Wp2, hB, 1024, 128, 128, nullptr, 0, 0);
    gemm_atb32<<<dim3(4, 32), 256, 0, stream>>>(an1, hB, s2, 1024, 128, 1024, bp2, 1);

    // --- diff_pool level 2 ---
    k_softmax_ent<<<1024, 256, 0, stream>>>(s2, S2s, 128, nullptr, &scal[5]);
    gemm_ab32<<<dim3(4, 32), 256, 0, stream>>>(adj1o, S2s, u, 1024, 128, 1024, nullptr, 0, 0);
    gemm_atb32<<<dim3(4, 4), 256, 0, stream>>>(S2s, x1_, x2, 128, 128, 1024, nullptr, 0);
    gemm_atb32<<<dim3(4, 4), 256, 0, stream>>>(S2s, u, adj2, 128, 128, 1024, nullptr, 0);
    k_l2<<<1024, 128, 0, stream>>>(adj1o, S2s, &scal[4]);

    // --- a_norm for adj2, level 2 GCN ---
    hipMemsetAsync(curr, 0, 128 * sizeof(float), stream);
    k_colsum<<<dim3(1, 2), 128, 0, stream>>>(adj2, 128, (float*)curr);
    k_dfix<<<1, 128, 0, stream>>>(adj2, 128, (float*)curr, di2, df2);
    k_anorm<<<64, 256, 0, stream>>>(adj2, 128, di2, df2, an2);
    gemm_ab32<<<dim3(4, 4), 256, 0, stream>>>(x2, W2_in, hC, 128, 128, 128, nullptr, 0, 0);
    gemm_atb32<<<dim3(4, 4), 256, 0, stream>>>(an2, hC, x2_, 128, 128, 128, b2_in, 1);

    // --- unpool to level 1:  hcat = x1_@W1o1 + s2@(x2_@W1o2) ---
    gemm_ab32<<<dim3(4, 4), 256, 0, stream>>>(x2_, W1_out + 128 * 128, z2, 128, 128, 128, nullptr, 0, 0);
    gemm_ab32<<<dim3(4, 32), 256, 0, stream>>>(x1_, W1_out, hcat, 1024, 128, 128, nullptr, 0, 0);
    gemm_ab32<<<dim3(4, 32), 256, 0, stream>>>(s2, z2, hcat, 1024, 128, 128, nullptr, 0, 1);
    gemm_atb32<<<dim3(4, 32), 256, 0, stream>>>(an1, hcat, x1o_, 1024, 128, 1024, b1_out, 1);

    // --- unpool to level 0:  p16 = x0_@W0out1 + s1o@(x1o_@W0out2) ---
    k_gemm_n16<<<64, 256, 0, stream>>>(x1o_, W0_out + 128 * 16, hA /*=y*/, 1024, 128, 0);
    k_gemm_n16<<<512, 256, 0, stream>>>(x0_, W0_out, p16, 8192, 128, 0);
    k_gemm_n16<<<512, 256, 0, stream>>>(s1o, hA /*=y*/, p16, 8192, 1024, 1);
    k_agg16<<<512, 256, 0, stream>>>(p16, h16, cptr, colr, coln, dinv, b0_out);
    k_logsoftmax<<<32, 256, 0, stream>>>(h16, predo, N);

    k_finalize<<<1, 64, 0, stream>>>(scal, losso);
}

// Round 4
// 1313.393 us; speedup vs baseline: 4.9574x; 1.0876x over previous
//
#include <hip/hip_runtime.h>
#include <math.h>

// ---------------------------------------------------------------------------
// DiffPool GNN (N=8192, E=262144, F=H=128, C1=1024, C2=128, NC=16).
// R4: all gather paths (spmm, GCN agg) moved to bf16; single-pass fused
// softmax writing bf16 S; h0 stored bf16 by gemm epilogue.
// ---------------------------------------------------------------------------

#define N_NODES 8192
#define N_EDGES 262144

typedef __attribute__((ext_vector_type(8))) short short8;
typedef __attribute__((ext_vector_type(4))) float floatx4;

// ---------------- workspace layout (float-slot offsets, all 16-aligned) ----------------
#define OFF_DEG     0           // 8192  (zeroed)
#define OFF_CNTC    8192        // 8192  (zeroed)
#define OFF_CNTR    16384       // 8192  (zeroed)
#define OFF_SCAL    24576       // 16    (zeroed)  [0]=e1 [1]=cross [2]=g2 [3]=sumA2 [4]=l2 [5]=e2
#define ZERO_FLOATS 24592
#define OFF_COLPTR  24592       // 8193
#define OFF_ROWPTR  32785       // 8193
#define OFF_CURC    40978       // 8192 (later: colsum scratch)
#define OFF_CURR    49170       // 8192 (later: colsum scratch)
#define OFF_COLR    57362       // E (int)
#define OFF_COLN    319506      // E
#define OFF_ROWC    581650      // E (int)
#define OFF_ROWW    843794      // E
#define OFF_DINV    1105938     // 8192
#define OFF_X0      1114144     // 8192*128 fp32 (x0_, live to the end)
#define OFF_H0      2162720     // h0b bf16 [8192][128]; later G fp32 [1024][1024]
#define OFF_G       OFF_H0
// Region A:
#define OFF_S       3211296     // Sb bf16 [8192][1024] (4M slots); then TT bf16; then an1 fp32
#define OFF_TT      OFF_S
#define OFF_AN1     OFF_S
#define OFF_X0T     7405600     // bf16 [128][8192] (524288 slots)
#define OFF_X0B     7929888     // bf16 [8192][128] (524288 slots)
#define A2          8454176
#define OFF_X1      (A2+0)            // 1024*128
#define OFF_HA      (A2+131072)       // 1024*128 (later: y 1024*16)
#define OFF_X1_     (A2+262144)
#define OFF_HB      (A2+393216)
#define OFF_S2      (A2+524288)
#define OFF_S2S     (A2+655360)
#define OFF_U       (A2+786432)
#define OFF_X2      (A2+917504)       // 128*128
#define OFF_ADJ2    (A2+933888)
#define OFF_HC      (A2+950272)
#define OFF_X2_     (A2+966656)
#define OFF_AN2     (A2+983040)
#define OFF_Z2      (A2+999424)       // 128*128
#define OFF_HCAT    (A2+1130496)      // 1024*128
#define OFF_X1O     (A2+1261568)      // 1024*128
#define OFF_P16     (A2+1392640)      // 8192*16
#define OFF_H16     (A2+1523712)
#define OFF_DI1     (A2+1654784)      // 1024
#define OFF_DF1     (A2+1655808)
#define OFF_DI2     (A2+1656832)      // 128
#define OFF_DF2     (A2+1656960)      // ends A2+1657088 = 10111264
// Region B:
#define OFF_ST      10111264          // S_T bf16 [1024][8192] (4M slots)
#define OFF_TBF     14305568          // t bf16 [8192][1024] (4M slots); WP1T aliases start
#define OFF_WP1T    OFF_TBF
// total ws: 18,499,872 float-slots = 70.6 MiB (< R3's 76.3 MiB)

// ------------------- output layout (floats) -------------------
#define OUT_PRED 0          // 8192*16
#define OUT_S1   131072     // 8192*1024
#define OUT_LOSS 8519680    // 1
#define OUT_ADJ1 8519681    // 1024*1024

__device__ __forceinline__ unsigned short f2bf(float f) {
    union { float f; unsigned u; } v; v.f = f;
    unsigned r = (v.u + 0x7FFF + ((v.u >> 16) & 1)) >> 16;
    return (unsigned short)r;
}
__device__ __forceinline__ float bf2f(unsigned short b) {
    union { unsigned u; float f; } v; v.u = (unsigned)b << 16; return v.f;
}

// =========================== graph-structure kernels ===========================

__global__ void k_hist(const int* __restrict__ row, const int* __restrict__ col,
                       const float* __restrict__ ew, int E,
                       float* deg, int* cntc, int* cntr, float* sumA2) {
    __shared__ float red[256];
    int e = blockIdx.x * 256 + threadIdx.x;
    float w2 = 0.f;
    if (e < E) {
        int r = row[e], c = col[e];
        float w = ew[e];
        atomicAdd(&deg[c], w);
        atomicAdd(&cntc[c], 1);
        atomicAdd(&cntr[r], 1);
        w2 = w * w;
    }
    red[threadIdx.x] = w2; __syncthreads();
    for (int s = 128; s > 0; s >>= 1) { if (threadIdx.x < s) red[threadIdx.x] += red[threadIdx.x + s]; __syncthreads(); }
    if (threadIdx.x == 0) atomicAdd(sumA2, red[0]);
}

__global__ void k_dinv(const float* deg, float* dinv, int n) {
    int i = blockIdx.x * 256 + threadIdx.x;
    if (i < n) {
        float d = deg[i] + 1.0f;
        dinv[i] = (d > 0.f) ? 1.0f / sqrtf(d) : 0.f;
    }
}

__global__ __launch_bounds__(1024) void k_scan(const int* cntc, const int* cntr,
        int* colptr, int* rowptr, int* curc, int* curr, int n, int E) {
    __shared__ int part[1024];
    int tid = threadIdx.x;
    const int per = 8;
    for (int pass = 0; pass < 2; ++pass) {
        const int* cnt = pass ? cntr : cntc;
        int* ptr = pass ? rowptr : colptr;
        int* cur = pass ? curr : curc;
        int st = tid * per;
        int loc[per]; int s = 0;
        for (int i = 0; i < per; ++i) { loc[i] = s; s += cnt[st + i]; }
        part[tid] = s; __syncthreads();
        for (int off = 1; off < 1024; off <<= 1) {
            int v = part[tid];
            int add = (tid >= off) ? part[tid - off] : 0;
            __syncthreads();
            part[tid] = v + add;
            __syncthreads();
        }
        int pre = (tid == 0) ? 0 : part[tid - 1];
        for (int i = 0; i < per; ++i) { int v = pre + loc[i]; ptr[st + i] = v; cur[st + i] = v; }
        if (tid == 0) ptr[n] = E;
        __syncthreads();
    }
}

__global__ void k_scatter(const int* __restrict__ row, const int* __restrict__ col,
                          const float* __restrict__ ew, int E, const float* __restrict__ dinv,
                          int* curc, int* curr, int* colr, float* coln, int* rowc, float* roww) {
    int e = blockIdx.x * 256 + threadIdx.x;
    if (e >= E) return;
    int r = row[e], c = col[e];
    float w = ew[e];
    float nrm = dinv[r] * w * dinv[c];
    int p = atomicAdd(&curc[c], 1);
    colr[p] = r; coln[p] = nrm;
    int q = atomicAdd(&curr[r], 1);
    rowc[q] = c; roww[q] = w;
}

// =========================== fp32 GEMMs ===========================

// 64x64 tile, bf16 output (used once: h0b = x0 @ W0_in)
__global__ __launch_bounds__(256) void gemm_ab_b16(const float* __restrict__ A, const float* __restrict__ B,
        unsigned short* __restrict__ C, int M, int N, int K) {
    __shared__ float As[16][68];
    __shared__ float Bs[16][68];
    int tid = threadIdx.x, tx = tid & 15, ty = tid >> 4;
    int m0 = blockIdx.y * 64, n0 = blockIdx.x * 64;
    float acc[4][4] = {};
    for (int k0 = 0; k0 < K; k0 += 16) {
        for (int l = 0; l < 4; ++l) {
            int idx = tid + 256 * l;
            int mm = idx >> 4, kk = idx & 15;
            As[kk][mm] = A[(size_t)(m0 + mm) * K + k0 + kk];
            int kk2 = idx >> 6, nn = idx & 63;
            Bs[kk2][nn] = B[(size_t)(k0 + kk2) * N + n0 + nn];
        }
        __syncthreads();
        #pragma unroll
        for (int kk = 0; kk < 16; ++kk) {
            float a[4], b[4];
            #pragma unroll
            for (int i = 0; i < 4; ++i) a[i] = As[kk][ty * 4 + i];
            #pragma unroll
            for (int j = 0; j < 4; ++j) b[j] = Bs[kk][tx * 4 + j];
            #pragma unroll
            for (int i = 0; i < 4; ++i)
                #pragma unroll
                for (int j = 0; j < 4; ++j) acc[i][j] += a[i] * b[j];
        }
        __syncthreads();
    }
    for (int i = 0; i < 4; ++i)
        for (int j = 0; j < 4; ++j)
            C[(size_t)(m0 + ty * 4 + i) * N + n0 + tx * 4 + j] = f2bf(acc[i][j]);
}

// 32x32 tile, C = A@B (+bias/relu/accum). Dims multiples of 32.
__global__ __launch_bounds__(256) void gemm_ab32(const float* __restrict__ A, const float* __restrict__ B,
        float* __restrict__ C, int M, int N, int K,
        const float* __restrict__ bias, int relu, int accum) {
    __shared__ float As[32][33];
    __shared__ float Bs[32][33];
    int tid = threadIdx.x, tx = tid & 15, ty = tid >> 4;
    int m0 = blockIdx.y * 32, n0 = blockIdx.x * 32;
    float acc[2][2] = {};
    for (int k0 = 0; k0 < K; k0 += 32) {
        #pragma unroll
        for (int l = 0; l < 4; ++l) {
            int idx = tid + 256 * l;
            int r = idx >> 5, c = idx & 31;
            As[r][c] = A[(size_t)(m0 + r) * K + k0 + c];
            Bs[r][c] = B[(size_t)(k0 + r) * N + n0 + c];
        }
        __syncthreads();
        #pragma unroll
        for (int kk = 0; kk < 32; ++kk) {
            float a0 = As[ty * 2][kk], a1 = As[ty * 2 + 1][kk];
            float b0 = Bs[kk][tx * 2], b1 = Bs[kk][tx * 2 + 1];
            acc[0][0] += a0 * b0; acc[0][1] += a0 * b1;
            acc[1][0] += a1 * b0; acc[1][1] += a1 * b1;
        }
        __syncthreads();
    }
    #pragma unroll
    for (int i = 0; i < 2; ++i)
        #pragma unroll
        for (int j = 0; j < 2; ++j) {
            int m = m0 + ty * 2 + i, n = n0 + tx * 2 + j;
            float v = acc[i][j];
            if (accum) v += C[(size_t)m * N + n];
            if (bias) v += bias[n];
            if (relu) v = fmaxf(v, 0.f);
            C[(size_t)m * N + n] = v;
        }
}

// 32x32 tile, C = A^T@B with A[K][M], B[K][N].
__global__ __launch_bounds__(256) void gemm_atb32(const float* __restrict__ A, const float* __restrict__ B,
        float* __restrict__ C, int M, int N, int K,
        const float* __restrict__ bias, int relu) {
    __shared__ float As[32][33];
    __shared__ float Bs[32][33];
    int tid = threadIdx.x, tx = tid & 15, ty = tid >> 4;
    int m0 = blockIdx.y * 32, n0 = blockIdx.x * 32;
    float acc[2][2] = {};
    for (int k0 = 0; k0 < K; k0 += 32) {
        #pragma unroll
        for (int l = 0; l < 4; ++l) {
            int idx = tid + 256 * l;
            int r = idx >> 5, c = idx & 31;
            As[c][r] = A[(size_t)(k0 + r) * M + m0 + c];
            Bs[r][c] = B[(size_t)(k0 + r) * N + n0 + c];
        }
        __syncthreads();
        #pragma unroll
        for (int kk = 0; kk < 32; ++kk) {
            float a0 = As[ty * 2][kk], a1 = As[ty * 2 + 1][kk];
            float b0 = Bs[kk][tx * 2], b1 = Bs[kk][tx * 2 + 1];
            acc[0][0] += a0 * b0; acc[0][1] += a0 * b1;
            acc[1][0] += a1 * b0; acc[1][1] += a1 * b1;
        }
        __syncthreads();
    }
    #pragma unroll
    for (int i = 0; i < 2; ++i)
        #pragma unroll
        for (int j = 0; j < 2; ++j) {
            int m = m0 + ty * 2 + i, n = n0 + tx * 2 + j;
            float v = acc[i][j];
            if (bias) v += bias[n];
            if (relu) v = fmaxf(v, 0.f);
            C[(size_t)m * N + n] = v;
        }
}

// C[M][16] (+)= A[M][K] @ B[K][16].  K multiple of 64, M multiple of 16.
__global__ __launch_bounds__(256) void k_gemm_n16(const float* __restrict__ A, const float* __restrict__ B,
        float* __restrict__ C, int M, int K, int accum) {
    __shared__ float As[16][64];
    __shared__ float Bs[64][16];
    int tid = threadIdx.x;
    int r = tid >> 4, c = tid & 15;
    int m0 = blockIdx.x * 16;
    float acc = 0.f;
    for (int k0 = 0; k0 < K; k0 += 64) {
        #pragma unroll
        for (int l = 0; l < 4; ++l) {
            int idx = tid + 256 * l;
            int rr = idx >> 6, cc = idx & 63;
            As[rr][cc] = A[(size_t)(m0 + rr) * K + k0 + cc];
            int kk = idx >> 4, c2 = idx & 15;
            Bs[kk][c2] = B[(size_t)(k0 + kk) * 16 + c2];
        }
        __syncthreads();
        #pragma unroll 16
        for (int kk = 0; kk < 64; ++kk) acc += As[r][kk] * Bs[kk][c];
        __syncthreads();
    }
    float* p = &C[(size_t)(m0 + r) * 16 + c];
    if (accum) acc += *p;
    *p = acc;
}

// =========================== bf16 MFMA GEMMs ===========================

// split-K atomic accumulate version
__global__ __launch_bounds__(256) void gemm_tn_bf16(
        const unsigned short* __restrict__ A, const unsigned short* __restrict__ B,
        float* __restrict__ C, int M, int N, int K, int ksplit) {
    __shared__ __align__(16) unsigned short As[128 * 64];
    __shared__ __align__(16) unsigned short Bs[128 * 64];
    int tid = threadIdx.x;
    int wave = tid >> 6, lane = tid & 63;
    int wm = wave >> 1, wn = wave & 1;
    int m0 = blockIdx.x * 128, n0 = blockIdx.y * 128;
    int kchunk = K / ksplit;
    int k0 = blockIdx.z * kchunk;
    floatx4 acc[4][4] = {};
    int sr = tid >> 3;
    int sc = (tid & 7) * 8;
    int q = lane >> 4, lm = lane & 15;
    for (int kt = 0; kt < kchunk; kt += 64) {
        #pragma unroll
        for (int p = 0; p < 4; ++p) {
            int mrow = sr + p * 32;
            int gk = k0 + kt + sc;
            int scs = sc ^ ((mrow & 7) * 8);
            *(short8*)(&As[mrow * 64 + scs]) = *(const short8*)(&A[(size_t)(m0 + mrow) * K + gk]);
            *(short8*)(&Bs[mrow * 64 + scs]) = *(const short8*)(&B[(size_t)(n0 + mrow) * K + gk]);
        }
        __syncthreads();
        #pragma unroll
        for (int ks = 0; ks < 64; ks += 32) {
            short8 af[4], bf[4];
            int kk = ks + q * 8;
            #pragma unroll
            for (int i = 0; i < 4; ++i) {
                int ml = wm * 64 + i * 16 + lm;
                af[i] = *(const short8*)(&As[ml * 64 + (kk ^ ((ml & 7) * 8))]);
                int nl = wn * 64 + i * 16 + lm;
                bf[i] = *(const short8*)(&Bs[nl * 64 + (kk ^ ((nl & 7) * 8))]);
            }
            #pragma unroll
            for (int i = 0; i < 4; ++i)
                #pragma unroll
                for (int j = 0; j < 4; ++j)
                    acc[i][j] = __builtin_amdgcn_mfma_f32_16x16x32_bf16(af[i], bf[j], acc[i][j], 0, 0, 0);
        }
        __syncthreads();
    }
    for (int i = 0; i < 4; ++i) {
        int rowb = m0 + wm * 64 + i * 16 + q * 4;
        for (int j = 0; j < 4; ++j) {
            int col = n0 + wn * 64 + j * 16 + lm;
            #pragma unroll
            for (int r = 0; r < 4; ++r)
                atomicAdd(&C[(size_t)(rowb + r) * N + col], acc[i][j][r]);
        }
    }
}

// full-K store version with bias+relu (for s1o)
__global__ __launch_bounds__(256) void gemm_tn_bf16_store(
        const unsigned short* __restrict__ A, const unsigned short* __restrict__ B,
        float* __restrict__ C, int M, int N, int K,
        const float* __restrict__ bias, int relu) {
    __shared__ __align__(16) unsigned short As[128 * 64];
    __shared__ __align__(16) unsigned short Bs[128 * 64];
    int tid = threadIdx.x;
    int wave = tid >> 6, lane = tid & 63;
    int wm = wave >> 1, wn = wave & 1;
    int m0 = blockIdx.x * 128, n0 = blockIdx.y * 128;
    floatx4 acc[4][4] = {};
    int sr = tid >> 3;
    int sc = (tid & 7) * 8;
    int q = lane >> 4, lm = lane & 15;
    for (int kt = 0; kt < K; kt += 64) {
        #pragma unroll
        for (int p = 0; p < 4; ++p) {
            int mrow = sr + p * 32;
            int gk = kt + sc;
            int scs = sc ^ ((mrow & 7) * 8);
            *(short8*)(&As[mrow * 64 + scs]) = *(const short8*)(&A[(size_t)(m0 + mrow) * K + gk]);
            *(short8*)(&Bs[mrow * 64 + scs]) = *(const short8*)(&B[(size_t)(n0 + mrow) * K + gk]);
        }
        __syncthreads();
        #pragma unroll
        for (int ks = 0; ks < 64; ks += 32) {
            short8 af[4], bf[4];
            int kk = ks + q * 8;
            #pragma unroll
            for (int i = 0; i < 4; ++i) {
                int ml = wm * 64 + i * 16 + lm;
                af[i] = *(const short8*)(&As[ml * 64 + (kk ^ ((ml & 7) * 8))]);
                int nl = wn * 64 + i * 16 + lm;
                bf[i] = *(const short8*)(&Bs[nl * 64 + (kk ^ ((nl & 7) * 8))]);
            }
            #pragma unroll
            for (int i = 0; i < 4; ++i)
                #pragma unroll
                for (int j = 0; j < 4; ++j)
                    acc[i][j] = __builtin_amdgcn_mfma_f32_16x16x32_bf16(af[i], bf[j], acc[i][j], 0, 0, 0);
        }
        __syncthreads();
    }
    for (int i = 0; i < 4; ++i) {
        int rowb = m0 + wm * 64 + i * 16 + q * 4;
        for (int j = 0; j < 4; ++j) {
            int col = n0 + wn * 64 + j * 16 + lm;
            float bv = bias ? bias[col] : 0.f;
            #pragma unroll
            for (int r = 0; r < 4; ++r) {
                float v = acc[i][j][r] + bv;
                if (relu) v = fmaxf(v, 0.f);
                C[(size_t)(rowb + r) * N + col] = v;
            }
        }
    }
}

// =========================== transposes ===========================

// fp32 in[R][C] -> bf16 out[C][R], optional per-row scale. R,C multiples of 64.
__global__ __launch_bounds__(256) void k_transpose_f2b(
        const float* __restrict__ in, unsigned short* __restrict__ outb,
        int R, int C, const float* __restrict__ rowscale) {
    __shared__ float tile[64][65];
    int rb = blockIdx.y * 64, cb = blockIdx.x * 64;
    int t = threadIdx.x;
    int lr = t >> 4, lc4 = (t & 15) * 4;
    #pragma unroll
    for (int p = 0; p < 4; ++p) {
        int r = rb + lr + p * 16;
        float4 v = *(const float4*)(in + (size_t)r * C + cb + lc4);
        float s = rowscale ? rowscale[r] : 1.0f;
        tile[lr + p * 16][lc4 + 0] = v.x * s;
        tile[lr + p * 16][lc4 + 1] = v.y * s;
        tile[lr + p * 16][lc4 + 2] = v.z * s;
        tile[lr + p * 16][lc4 + 3] = v.w * s;
    }
    __syncthreads();
    int cc0 = t >> 5, rr = (t & 31) * 2;
    #pragma unroll
    for (int p = 0; p < 8; ++p) {
        int cc = cc0 + p * 8;
        unsigned a = f2bf(tile[rr][cc]);
        unsigned b = f2bf(tile[rr + 1][cc]);
        *(unsigned*)(outb + (size_t)(cb + cc) * R + rb + rr) = a | (b << 16);
    }
}

// bf16 in[R][C] -> bf16 out[C][R]. R,C multiples of 64.
__global__ __launch_bounds__(256) void k_transpose_b2b(
        const unsigned short* __restrict__ in, unsigned short* __restrict__ out, int R, int C) {
    __shared__ __align__(16) unsigned short tile[64][72];
    int rb = blockIdx.y * 64, cb = blockIdx.x * 64;
    int t = threadIdx.x;
    int lr = t >> 3, lc = (t & 7) * 8;
    #pragma unroll
    for (int p = 0; p < 2; ++p) {
        int r = lr + p * 32;
        *(short8*)(&tile[r][lc]) = *(const short8*)(&in[(size_t)(rb + r) * C + cb + lc]);
    }
    __syncthreads();
    int cc0 = t >> 4, rr = (t & 15) * 4;
    #pragma unroll
    for (int p = 0; p < 4; ++p) {
        int cc = cc0 + p * 16;
        unsigned long long v = (unsigned long long)tile[rr][cc]
                             | ((unsigned long long)tile[rr + 1][cc] << 16)
                             | ((unsigned long long)tile[rr + 2][cc] << 32)
                             | ((unsigned long long)tile[rr + 3][cc] << 48);
        *(unsigned long long*)(&out[(size_t)(cb + cc) * R + rb + rr]) = v;
    }
}

// =========================== aggregation / misc ===========================

// GCN sparse aggregation, bf16 gather (F=128 fixed), 64 threads = 1 wave, 2 cols/thread.
__global__ __launch_bounds__(64) void k_agg_b16(const unsigned short* __restrict__ h,
        float* __restrict__ out, unsigned short* __restrict__ outb,
        const int* __restrict__ cptr, const int* __restrict__ colr,
        const float* __restrict__ coln, const float* __restrict__ dinv,
        const float* __restrict__ bias, int relu) {
    int c = blockIdx.x, t = threadIdx.x;
    int f0 = t * 2;
    float d = dinv[c], dd = d * d;
    unsigned u = *(const unsigned*)(h + (size_t)c * 128 + f0);
    float a0 = dd * bf2f((unsigned short)(u & 0xffff));
    float a1 = dd * bf2f((unsigned short)(u >> 16));
    int e0 = cptr[c], e1 = cptr[c + 1];
    for (int e = e0; e < e1; ++e) {
        float w = coln[e];
        unsigned v = *(const unsigned*)(h + (size_t)colr[e] * 128 + f0);
        a0 += w * bf2f((unsigned short)(v & 0xffff));
        a1 += w * bf2f((unsigned short)(v >> 16));
    }
    if (bias) { a0 += bias[f0]; a1 += bias[f0 + 1]; }
    if (relu) { a0 = fmaxf(a0, 0.f); a1 = fmaxf(a1, 0.f); }
    if (out) { out[(size_t)c * 128 + f0] = a0; out[(size_t)c * 128 + f0 + 1] = a1; }
    if (outb) {
        unsigned o = (unsigned)f2bf(a0) | ((unsigned)f2bf(a1) << 16);
        *(unsigned*)(outb + (size_t)c * 128 + f0) = o;
    }
}

// F=16 variant: 16 nodes per block.
__global__ __launch_bounds__(256) void k_agg16(const float* __restrict__ h, float* __restrict__ out,
        const int* __restrict__ cptr, const int* __restrict__ colr,
        const float* __restrict__ coln, const float* __restrict__ dinv,
        const float* __restrict__ bias) {
    int node = blockIdx.x * 16 + (threadIdx.x >> 4);
    int f = threadIdx.x & 15;
    float d = dinv[node];
    float acc = d * d * h[(size_t)node * 16 + f];
    int e0 = cptr[node], e1 = cptr[node + 1];
    for (int e = e0; e < e1; ++e)
        acc += coln[e] * h[(size_t)colr[e] * 16 + f];
    acc += bias[f];
    out[(size_t)node * 16 + f] = fmaxf(acc, 0.f);
}

// single-pass softmax over W=1024, writes bf16 S (masked) + entropy.
__global__ __launch_bounds__(256) void k_softmax1024(const float* __restrict__ x,
        unsigned short* __restrict__ Sb, const float* __restrict__ mask, float* ent_acc) {
    __shared__ float red[256];
    int r = blockIdx.x, tid = threadIdx.x;
    const float* xr = x + (size_t)r * 1024;
    float4 v = *(const float4*)(xr + tid * 4);
    float m = fmaxf(fmaxf(v.x, v.y), fmaxf(v.z, v.w));
    red[tid] = m; __syncthreads();
    for (int s = 128; s > 0; s >>= 1) { if (tid < s) red[tid] = fmaxf(red[tid], red[tid + s]); __syncthreads(); }
    m = red[0]; __syncthreads();
    float e0 = expf(v.x - m), e1 = expf(v.y - m), e2 = expf(v.z - m), e3 = expf(v.w - m);
    red[tid] = e0 + e1 + e2 + e3; __syncthreads();
    for (int s = 128; s > 0; s >>= 1) { if (tid < s) red[tid] += red[tid + s]; __syncthreads(); }
    float inv = 1.0f / red[0]; __syncthreads();
    float mk = mask ? mask[r] : 1.0f;
    float s0 = e0 * inv * mk, s1 = e1 * inv * mk, s2 = e2 * inv * mk, s3 = e3 * inv * mk;
    float ent = -(s0 * logf(s0 + 1e-15f) + s1 * logf(s1 + 1e-15f)
                + s2 * logf(s2 + 1e-15f) + s3 * logf(s3 + 1e-15f));
    ushort4 o;
    o.x = f2bf(s0); o.y = f2bf(s1); o.z = f2bf(s2); o.w = f2bf(s3);
    *(ushort4*)(Sb + (size_t)r * 1024 + tid * 4) = o;
    red[tid] = ent; __syncthreads();
    for (int s = 128; s > 0; s >>= 1) { if (tid < s) red[tid] += red[tid + s]; __syncthreads(); }
    if (tid == 0) atomicAdd(ent_acc, red[0]);
}

// generic softmax (fp32 out) for s2 (W=128)
__global__ __launch_bounds__(256) void k_softmax_ent(const float* __restrict__ x, float* __restrict__ S,
        int W, const float* __restrict__ mask, float* ent_acc) {
    __shared__ float red[256];
    int row = blockIdx.x, tid = threadIdx.x;
    const float* xr = x + (size_t)row * W;
    float m = -3.0e38f;
    for (int q = tid; q < W; q += 256) m = fmaxf(m, xr[q]);
    red[tid] = m; __syncthreads();
    for (int s = 128; s > 0; s >>= 1) { if (tid < s) red[tid] = fmaxf(red[tid], red[tid + s]); __syncthreads(); }
    m = red[0]; __syncthreads();
    float sum = 0.f;
    for (int q = tid; q < W; q += 256) sum += expf(xr[q] - m);
    red[tid] = sum; __syncthreads();
    for (int s = 128; s > 0; s >>= 1) { if (tid < s) red[tid] += red[tid + s]; __syncthreads(); }
    float inv = 1.0f / red[0]; __syncthreads();
    float mk = mask ? mask[row] : 1.0f;
    float* Sr = S + (size_t)row * W;
    float ent = 0.f;
    for (int q = tid; q < W; q += 256) {
        float v = expf(xr[q] - m) * inv * mk;
        Sr[q] = v;
        ent -= v * logf(v + 1e-15f);
    }
    red[tid] = ent; __syncthreads();
    for (int s = 128; s > 0; s >>= 1) { if (tid < s) red[tid] += red[tid + s]; __syncthreads(); }
    if (tid == 0) atomicAdd(ent_acc, red[0]);
}

// t[r,:] = sum_e w_e Sb[c_e,:] (CSR, bf16 gather), bf16 out; cross += w<S[r],S[c]>
__global__ __launch_bounds__(256) void k_spmm_b16(const unsigned short* __restrict__ Sb,
        const int* __restrict__ rptr, const int* __restrict__ rowc, const float* __restrict__ roww,
        unsigned short* __restrict__ tb, float* cross_acc) {
    __shared__ float red[256];
    int r = blockIdx.x, tid = threadIdx.x;
    int c0 = tid * 4;
    ushort4 s4 = *(const ushort4*)(Sb + (size_t)r * 1024 + c0);
    float sr0 = bf2f(s4.x), sr1 = bf2f(s4.y), sr2 = bf2f(s4.z), sr3 = bf2f(s4.w);
    float a0 = 0.f, a1 = 0.f, a2 = 0.f, a3 = 0.f, lp = 0.f;
    int e0 = rptr[r], e1 = rptr[r + 1];
    for (int e = e0; e < e1; ++e) {
        int c = rowc[e]; float w = roww[e];
        ushort4 v4 = *(const ushort4*)(Sb + (size_t)c * 1024 + c0);
        float v0 = bf2f(v4.x), v1 = bf2f(v4.y), v2 = bf2f(v4.z), v3 = bf2f(v4.w);
        a0 += w * v0; a1 += w * v1; a2 += w * v2; a3 += w * v3;
        lp += w * (sr0 * v0 + sr1 * v1 + sr2 * v2 + sr3 * v3);
    }
    ushort4 o;
    o.x = f2bf(a0); o.y = f2bf(a1); o.z = f2bf(a2); o.w = f2bf(a3);
    *(ushort4*)(tb + (size_t)r * 1024 + c0) = o;
    red[tid] = lp; __syncthreads();
    for (int s = 128; s > 0; s >>= 1) { if (tid < s) red[tid] += red[tid + s]; __syncthreads(); }
    if (tid == 0) atomicAdd(cross_acc, red[0]);
}

__global__ __launch_bounds__(256) void k_sumsq(const float* __restrict__ g, int n, float* acc) {
    __shared__ float red[256];
    float s = 0.f;
    for (int i = blockIdx.x * 256 + threadIdx.x; i < n; i += gridDim.x * 256) { float v = g[i]; s += v * v; }
    red[threadIdx.x] = s; __syncthreads();
    for (int st = 128; st > 0; st >>= 1) { if (threadIdx.x < st) red[threadIdx.x] += red[threadIdx.x + st]; __syncthreads(); }
    if (threadIdx.x == 0) atomicAdd(acc, red[0]);
}

__global__ void k_colsum(const float* __restrict__ adjm, int n, float* colsum) {
    int j = blockIdx.x * blockDim.x + threadIdx.x;
    if (j >= n) return;
    int r0 = blockIdx.y * 64;
    float s = 0.f;
    for (int r = r0; r < r0 + 64; ++r) s += adjm[(size_t)r * n + j];
    atomicAdd(&colsum[j], s);
}

__global__ void k_dfix(const float* __restrict__ adjm, int n, const float* __restrict__ colsum,
                       float* dinvv, float* dfix) {
    int j = blockIdx.x * blockDim.x + threadIdx.x;
    if (j >= n) return;
    float diag = adjm[(size_t)j * n + j];
    float fix = (diag == 0.f) ? 1.0f : 0.f;
    float s = colsum[j] + fix;
    dfix[j] = fix;
    dinvv[j] = (s > 0.f) ? 1.0f / sqrtf(s) : 0.f;
}

__global__ void k_anorm(const float* __restrict__ adjm, int n, const float* __restrict__ dinvv,
                        const float* __restrict__ dfix, float* __restrict__ anorm) {
    int idx = blockIdx.x * 256 + threadIdx.x;
    if (idx >= n * n) return;
    int i = idx / n, j = idx % n;
    float v = adjm[idx] + ((i == j) ? dfix[j] : 0.f);
    anorm[idx] = dinvv[i] * v * dinvv[j];
}

__global__ __launch_bounds__(128) void k_l2(const float* __restrict__ adjm, const float* __restrict__ S2,
        float* acc) {
    __shared__ float sp[128];
    __shared__ float red[128];
    int p = blockIdx.x, tid = threadIdx.x;
    sp[tid] = S2[(size_t)p * 128 + tid];
    __syncthreads();
    float part = 0.f;
    for (int q = tid; q < 1024; q += 128) {
        const float* Sq = S2 + (size_t)q * 128;
        float dot = 0.f;
        #pragma unroll 8
        for (int k = 0; k < 128; ++k) dot += Sq[k] * sp[k];
        float d = adjm[(size_t)p * 1024 + q] - dot;
        part += d * d;
    }
    red[tid] = part; __syncthreads();
    for (int s = 64; s > 0; s >>= 1) { if (tid < s) red[tid] += red[tid + s]; __syncthreads(); }
    if (tid == 0) atomicAdd(acc, red[0]);
}

__global__ void k_logsoftmax(const float* __restrict__ x, float* __restrict__ out, int n) {
    int i = blockIdx.x * 256 + threadIdx.x;
    if (i >= n) return;
    float v[16];
    float m = -3.0e38f;
    #pragma unroll
    for (int j = 0; j < 16; ++j) { v[j] = x[(size_t)i * 16 + j]; m = fmaxf(m, v[j]); }
    float s = 0.f;
    #pragma unroll
    for (int j = 0; j < 16; ++j) s += expf(v[j] - m);
    float ls = m + logf(s);
    #pragma unroll
    for (int j = 0; j < 16; ++j) out[(size_t)i * 16 + j] = v[j] - ls;
}

__global__ void k_finalize(const float* __restrict__ sc, float* loss) {
    if (threadIdx.x == 0 && blockIdx.x == 0) {
        float e1    = sc[0] / 8192.0f;
        float cross = sc[1];
        float g2    = sc[2];
        float sumA2 = sc[3];
        float l2s   = sc[4];
        float e2    = sc[5] / 1024.0f;
        float l1 = sqrtf(fmaxf(sumA2 - 2.0f * cross + g2, 0.f)) / 67108864.0f;
        float l2 = sqrtf(fmaxf(l2s, 0.f)) / 1048576.0f;
        *loss = l1 + e1 + l2 + e2;
    }
}

// =========================== launcher ===========================

extern "C" void kernel_launch(void* const* d_in, const int* in_sizes, int n_in,
                              void* d_out, int out_size, void* d_ws, size_t ws_size,
                              hipStream_t stream) {
    const int N = N_NODES, E = N_EDGES;
    const float* x0     = (const float*)d_in[0];
    const int*   eidx   = (const int*)d_in[1];
    const float* ew     = (const float*)d_in[2];
    const float* mask   = (const float*)d_in[4];
    const float* W0_in  = (const float*)d_in[5];
    const float* b0_in  = (const float*)d_in[6];
    const float* Wp1    = (const float*)d_in[7];
    const float* bp1    = (const float*)d_in[8];
    const float* W1_in  = (const float*)d_in[9];
    const float* b1_in  = (const float*)d_in[10];
    const float* Wp2    = (const float*)d_in[11];
    const float* bp2    = (const float*)d_in[12];
    const float* W2_in  = (const float*)d_in[13];
    const float* b2_in  = (const float*)d_in[14];
    const float* W1_out = (const float*)d_in[15];
    const float* b1_out = (const float*)d_in[16];
    const float* W0_out = (const float*)d_in[17];
    const float* b0_out = (const float*)d_in[18];

    float* out   = (float*)d_out;
    float* predo = out + OUT_PRED;
    float* s1o   = out + OUT_S1;
    float* losso = out + OUT_LOSS;
    float* adj1o = out + OUT_ADJ1;

    float* wsf = (float*)d_ws;
    int*   wsi = (int*)d_ws;
    float* deg   = wsf + OFF_DEG;
    int*   cntc  = wsi + OFF_CNTC;
    int*   cntr  = wsi + OFF_CNTR;
    float* scal  = wsf + OFF_SCAL;
    int*   cptr  = wsi + OFF_COLPTR;
    int*   rptr  = wsi + OFF_ROWPTR;
    int*   curc  = wsi + OFF_CURC;
    int*   curr  = wsi + OFF_CURR;
    int*   colr  = wsi + OFF_COLR;
    float* coln  = wsf + OFF_COLN;
    int*   rowc  = wsi + OFF_ROWC;
    float* roww  = wsf + OFF_ROWW;
    float* dinv  = wsf + OFF_DINV;
    float* x0_   = wsf + OFF_X0;
    unsigned short* h0b  = (unsigned short*)(wsf + OFF_H0);
    float* G     = wsf + OFF_G;
    unsigned short* Sb   = (unsigned short*)(wsf + OFF_S);
    unsigned short* TT   = (unsigned short*)(wsf + OFF_TT);
    unsigned short* ST   = (unsigned short*)(wsf + OFF_ST);
    unsigned short* TBF  = (unsigned short*)(wsf + OFF_TBF);
    unsigned short* WP1T = (unsigned short*)(wsf + OFF_WP1T);
    unsigned short* X0T  = (unsigned short*)(wsf + OFF_X0T);
    unsigned short* x0b  = (unsigned short*)(wsf + OFF_X0B);
    float* an1   = wsf + OFF_AN1;
    float* x1    = wsf + OFF_X1;
    float* hA    = wsf + OFF_HA;
    float* x1_   = wsf + OFF_X1_;
    float* hB    = wsf + OFF_HB;
    float* s2    = wsf + OFF_S2;
    float* S2s   = wsf + OFF_S2S;
    float* u     = wsf + OFF_U;
    float* x2    = wsf + OFF_X2;
    float* adj2  = wsf + OFF_ADJ2;
    float* hC    = wsf + OFF_HC;
    float* x2_   = wsf + OFF_X2_;
    float* an2   = wsf + OFF_AN2;
    float* z2    = wsf + OFF_Z2;
    float* hcat  = wsf + OFF_HCAT;
    float* x1o_  = wsf + OFF_X1O;
    float* p16   = wsf + OFF_P16;
    float* h16   = wsf + OFF_H16;
    float* di1   = wsf + OFF_DI1;
    float* df1   = wsf + OFF_DF1;
    float* di2   = wsf + OFF_DI2;
    float* df2   = wsf + OFF_DF2;

    const int* row = eidx;
    const int* col = eidx + E;

    hipMemsetAsync(wsf, 0, (size_t)ZERO_FLOATS * sizeof(float), stream);

    // --- graph structure ---
    k_hist<<<E / 256, 256, 0, stream>>>(row, col, ew, E, deg, cntc, cntr, &scal[3]);
    k_dinv<<<N / 256, 256, 0, stream>>>(deg, dinv, N);
    k_scan<<<1, 1024, 0, stream>>>(cntc, cntr, cptr, rptr, curc, curr, N, E);
    k_scatter<<<E / 256, 256, 0, stream>>>(row, col, ew, E, dinv, curc, curr, colr, coln, rowc, roww);

    // --- level 0 GCN: h0b = x0@W0_in (bf16); x0_ (fp32) + x0b (bf16) ---
    gemm_ab_b16<<<dim3(2, 128), 256, 0, stream>>>(x0, W0_in, h0b, 8192, 128, 128);
    k_agg_b16<<<N, 64, 0, stream>>>(h0b, x0_, x0b, cptr, colr, coln, dinv, b0_in, 1);

    // --- s1 = relu((M^T x0_)@Wp1 + bp1): z bf16, MFMA ---
    k_agg_b16<<<N, 64, 0, stream>>>(x0b, nullptr, h0b, cptr, colr, coln, dinv, nullptr, 0);
    k_transpose_f2b<<<dim3(16, 2), 256, 0, stream>>>(Wp1, WP1T, 128, 1024, nullptr);
    gemm_tn_bf16_store<<<dim3(64, 8), 256, 0, stream>>>(h0b, WP1T, s1o, 8192, 1024, 128, bp1, 1);

    // --- diff_pool level 1 ---
    k_softmax1024<<<N, 256, 0, stream>>>(s1o, Sb, mask, &scal[0]);
    k_spmm_b16<<<N, 256, 0, stream>>>(Sb, rptr, rowc, roww, TBF, &scal[1]);
    k_transpose_b2b<<<dim3(16, 128), 256, 0, stream>>>(Sb, ST, 8192, 1024);    // Sb dead after
    k_transpose_b2b<<<dim3(16, 128), 256, 0, stream>>>(TBF, TT, 8192, 1024);   // TT overwrites Sb region
    k_transpose_f2b<<<dim3(2, 128), 256, 0, stream>>>(x0_, X0T, 8192, 128, mask);

    hipMemsetAsync(adj1o, 0, (size_t)1024 * 1024 * sizeof(float), stream);
    hipMemsetAsync(G,     0, (size_t)1024 * 1024 * sizeof(float), stream);
    hipMemsetAsync(x1,    0, (size_t)1024 * 128 * sizeof(float), stream);
    gemm_tn_bf16<<<dim3(8, 8, 8), 256, 0, stream>>>(ST, TT, adj1o, 1024, 1024, 8192, 8);
    gemm_tn_bf16<<<dim3(8, 8, 8), 256, 0, stream>>>(ST, ST, G, 1024, 1024, 8192, 8);
    gemm_tn_bf16<<<dim3(8, 1, 16), 256, 0, stream>>>(ST, X0T, x1, 1024, 128, 8192, 16);
    k_sumsq<<<256, 256, 0, stream>>>(G, 1024 * 1024, &scal[2]);

    // --- a_norm for adj1 (an1 overwrites TT region) ---
    hipMemsetAsync(curc, 0, 1024 * sizeof(float), stream);
    k_colsum<<<dim3(4, 16), 256, 0, stream>>>(adj1o, 1024, (float*)curc);
    k_dfix<<<4, 256, 0, stream>>>(adj1o, 1024, (float*)curc, di1, df1);
    k_anorm<<<4096, 256, 0, stream>>>(adj1o, 1024, di1, df1, an1);

    // --- level 1 dense GCNs ---
    gemm_ab32<<<dim3(4, 32), 256, 0, stream>>>(x1, W1_in, hA, 1024, 128, 128, nullptr, 0, 0);
    gemm_atb32<<<dim3(4, 32), 256, 0, stream>>>(an1, hA, x1_, 1024, 128, 1024, b1_in, 1);
    gemm_ab32<<<dim3(4, 32), 256, 0, stream>>>(x1_, Wp2, hB, 1024, 128, 128, nullptr, 0, 0);
    gemm_atb32<<<dim3(4, 32), 256, 0, stream>>>(an1, hB, s2, 1024, 128, 1024, bp2, 1);

    // --- diff_pool level 2 ---
    k_softmax_ent<<<1024, 256, 0, stream>>>(s2, S2s, 128, nullptr, &scal[5]);
    gemm_ab32<<<dim3(4, 32), 256, 0, stream>>>(adj1o, S2s, u, 1024, 128, 1024, nullptr, 0, 0);
    gemm_atb32<<<dim3(4, 4), 256, 0, stream>>>(S2s, x1_, x2, 128, 128, 1024, nullptr, 0);
    gemm_atb32<<<dim3(4, 4), 256, 0, stream>>>(S2s, u, adj2, 128, 128, 1024, nullptr, 0);
    k_l2<<<1024, 128, 0, stream>>>(adj1o, S2s, &scal[4]);

    // --- a_norm for adj2, level 2 GCN ---
    hipMemsetAsync(curr, 0, 128 * sizeof(float), stream);
    k_colsum<<<dim3(1, 2), 128, 0, stream>>>(adj2, 128, (float*)curr);
    k_dfix<<<1, 128, 0, stream>>>(adj2, 128, (float*)curr, di2, df2);
    k_anorm<<<64, 256, 0, stream>>>(adj2, 128, di2, df2, an2);
    gemm_ab32<<<dim3(4, 4), 256, 0, stream>>>(x2, W2_in, hC, 128, 128, 128, nullptr, 0, 0);
    gemm_atb32<<<dim3(4, 4), 256, 0, stream>>>(an2, hC, x2_, 128, 128, 128, b2_in, 1);

    // --- unpool to level 1:  hcat = x1_@W1o1 + s2@(x2_@W1o2) ---
    gemm_ab32<<<dim3(4, 4), 256, 0, stream>>>(x2_, W1_out + 128 * 128, z2, 128, 128, 128, nullptr, 0, 0);
    gemm_ab32<<<dim3(4, 32), 256, 0, stream>>>(x1_, W1_out, hcat, 1024, 128, 128, nullptr, 0, 0);
    gemm_ab32<<<dim3(4, 32), 256, 0, stream>>>(s2, z2, hcat, 1024, 128, 128, nullptr, 0, 1);
    gemm_atb32<<<dim3(4, 32), 256, 0, stream>>>(an1, hcat, x1o_, 1024, 128, 1024, b1_out, 1);

    // --- unpool to level 0:  p16 = x0_@W0out1 + s1o@(x1o_@W0out2) ---
    k_gemm_n16<<<64, 256, 0, stream>>>(x1o_, W0_out + 128 * 16, hA /*=y*/, 1024, 128, 0);
    k_gemm_n16<<<512, 256, 0, stream>>>(x0_, W0_out, p16, 8192, 128, 0);
    k_gemm_n16<<<512, 256, 0, stream>>>(s1o, hA /*=y*/, p16, 8192, 1024, 1);
    k_agg16<<<512, 256, 0, stream>>>(p16, h16, cptr, colr, coln, dinv, b0_out);
    k_logsoftmax<<<32, 256, 0, stream>>>(h16, predo, N);

    k_finalize<<<1, 64, 0, stream>>>(scal, losso);
}